// Round 9
// baseline (195.886 us; speedup 1.0000x reference)
//
#include <hip/hip_runtime.h>

#define NEG_SLOPE 0.2f

typedef __attribute__((ext_vector_type(4))) float f32x4;
typedef __attribute__((ext_vector_type(2))) float f32x2;
typedef __attribute__((ext_vector_type(8))) short short8;

__device__ __forceinline__ f32x2 mk2(float a, float b) { f32x2 r; r[0] = a; r[1] = b; return r; }

__device__ __forceinline__ f32x2 FMA2(f32x2 a, f32x2 b, f32x2 c) {
#if __has_builtin(__builtin_elementwise_fma)
    return __builtin_elementwise_fma(a, b, c);
#else
    f32x2 r; r[0] = fmaf(a[0], b[0], c[0]); r[1] = fmaf(a[1], b[1], c[1]); return r;
#endif
}

__device__ __forceinline__ ushort f2bf(float f) {
    uint u = __float_as_uint(f);
    u += 0x7FFFu + ((u >> 16) & 1u);
    return (ushort)(u >> 16);
}
__device__ __forceinline__ float bflo(uint u) { return __uint_as_float(u << 16); }
__device__ __forceinline__ float bfhi(uint u) { return __uint_as_float(u & 0xffff0000u); }

// ---------------- zero int buffer ----------------
__global__ __launch_bounds__(256) void k_zero_int(int* __restrict__ p, int n) {
    int i = blockIdx.x * 256 + threadIdx.x;
    if (i < n) p[i] = 0;
}

// ---------------- x (N x 512 f32) -> xpad (N x 544 bf16) cols 0..511 + zero pad 520..543 ----------------
__global__ __launch_bounds__(64) void k_prepX(const float* __restrict__ x, ushort* __restrict__ xpad) {
    const int n = blockIdx.x;
    const int t = threadIdx.x;
    float4 lo = *reinterpret_cast<const float4*>(&x[(size_t)n*512 + t*8]);
    float4 hi = *reinterpret_cast<const float4*>(&x[(size_t)n*512 + t*8 + 4]);
    uint4 w;
    w.x = (uint)f2bf(lo.x) | ((uint)f2bf(lo.y) << 16);
    w.y = (uint)f2bf(lo.z) | ((uint)f2bf(lo.w) << 16);
    w.z = (uint)f2bf(hi.x) | ((uint)f2bf(hi.y) << 16);
    w.w = (uint)f2bf(hi.z) | ((uint)f2bf(hi.w) << 16);
    *reinterpret_cast<uint4*>(&xpad[(size_t)n*544 + t*8]) = w;
    if (t == 0) {
        const uint4 z = make_uint4(0,0,0,0);
        *reinterpret_cast<uint4*>(&xpad[(size_t)n*544 + 520]) = z;
        *reinterpret_cast<uint4*>(&xpad[(size_t)n*544 + 528]) = z;
        *reinterpret_cast<uint4*>(&xpad[(size_t)n*544 + 536]) = z;
    }
}

// ---------------- per-node conv pipe, wave-per-node; readout written as bf16 into xpad cols 512..519 ----------------
__global__ __launch_bounds__(256) void k_conv_wave(
    const float* __restrict__ onehot,
    const float* __restrict__ c1w, const float* __restrict__ c1b,
    const float* __restrict__ c2w, const float* __restrict__ c2b,
    const float* __restrict__ l2w, const float* __restrict__ l2b,
    ushort* __restrict__ xpad, uint* __restrict__ ohb, int N) {
    const int wave = threadIdx.x >> 6;
    const int lane = threadIdx.x & 63;
    const int n = blockIdx.x * 4 + wave;
    if (n >= N) return;

    float2 in2 = *reinterpret_cast<const float2*>(&onehot[(size_t)n * 128 + lane * 2]);
    ohb[(size_t)n*64 + lane] = (uint)f2bf(in2.x) | ((uint)f2bf(in2.y) << 16);
    float v0 = log1pf(in2.x);
    float v1 = log1pf(in2.y);

    // bitonic sort of 128 elements, i = 2*lane + r; fully in registers
    #pragma unroll
    for (int k = 2; k <= 128; k <<= 1) {
        const bool asc = ((lane & (k >> 1)) == 0);
        #pragma unroll
        for (int j = k >> 1; j >= 2; j >>= 1) {
            const int m = j >> 1;
            float p0 = __shfl_xor(v0, m, 64);
            float p1 = __shfl_xor(v1, m, 64);
            const bool keepmin = (((lane & m) == 0) == asc);
            v0 = keepmin ? fminf(v0, p0) : fmaxf(v0, p0);
            v1 = keepmin ? fminf(v1, p1) : fmaxf(v1, p1);
        }
        float lo = fminf(v0, v1), hi = fmaxf(v0, v1);
        v0 = asc ? lo : hi;
        v1 = asc ? hi : lo;
    }

    float pm = __shfl_up(v1, 1, 64); if (lane == 0)  pm = 0.f;
    float pp = __shfl_down(v0, 1, 64); if (lane == 63) pp = 0.f;

    // conv1: 1->8, packed over the lane's two positions
    float h0[8], h1[8];
    {
        const f32x2 xm = mk2(pm, v0), x0 = mk2(v0, v1), xp = mk2(v1, pp);
        #pragma unroll
        for (int c = 0; c < 8; ++c) {
            const float w0 = c1w[c*3+0], w1 = c1w[c*3+1], w2 = c1w[c*3+2], b = c1b[c];
            f32x2 h = FMA2(xm, mk2(w0, w0), FMA2(x0, mk2(w1, w1), FMA2(xp, mk2(w2, w2), mk2(b, b))));
            h0[c] = fmaxf(h[0], 0.f);
            h1[c] = fmaxf(h[1], 0.f);
        }
    }

    // conv2: 8->16, packed
    f32x2 a01[16];
    #pragma unroll
    for (int c = 0; c < 16; ++c) { float b = c2b[c]; a01[c] = mk2(b, b); }
    #pragma unroll
    for (int ci = 0; ci < 8; ++ci) {
        float hm = __shfl_up(h1[ci], 1, 64); if (lane == 0)  hm = 0.f;
        float hp = __shfl_down(h0[ci], 1, 64); if (lane == 63) hp = 0.f;
        const f32x2 xm = mk2(hm, h0[ci]), x0 = mk2(h0[ci], h1[ci]), xp = mk2(h1[ci], hp);
        #pragma unroll
        for (int c = 0; c < 16; ++c) {
            const float w0 = c2w[(c*8+ci)*3+0], w1 = c2w[(c*8+ci)*3+1], w2 = c2w[(c*8+ci)*3+2];
            a01[c] = FMA2(xm, mk2(w0, w0), FMA2(x0, mk2(w1, w1), FMA2(xp, mk2(w2, w2), a01[c])));
        }
    }

    // relu + in-lane pair sum
    float pv[16];
    #pragma unroll
    for (int c = 0; c < 16; ++c) pv[c] = fmaxf(a01[c][0], 0.f) + fmaxf(a01[c][1], 0.f);

    // channel-splitting tree reduction: 17 shuffles total.
    {
        const bool up1 = lane & 1;
        #pragma unroll
        for (int j = 0; j < 8; ++j) {
            float send = up1 ? pv[j] : pv[j+8];
            float keep = up1 ? pv[j+8] : pv[j];
            pv[j] = keep + __shfl_xor(send, 1, 64);
        }
        const bool up2 = (lane >> 1) & 1;
        #pragma unroll
        for (int j = 0; j < 4; ++j) {
            float send = up2 ? pv[j] : pv[j+4];
            float keep = up2 ? pv[j+4] : pv[j];
            pv[j] = keep + __shfl_xor(send, 2, 64);
        }
        const bool up3 = (lane >> 2) & 1;
        #pragma unroll
        for (int j = 0; j < 2; ++j) {
            float send = up3 ? pv[j] : pv[j+2];
            float keep = up3 ? pv[j+2] : pv[j];
            pv[j] = keep + __shfl_xor(send, 4, 64);
        }
        const bool up4 = (lane >> 3) & 1;
        {
            float send = up4 ? pv[0] : pv[1];
            float keep = up4 ? pv[1] : pv[0];
            pv[0] = keep + __shfl_xor(send, 8, 64);
        }
        pv[0] += __shfl_xor(pv[0], 16, 64);
        pv[0] += __shfl_xor(pv[0], 32, 64);
    }

    // gather pooled[c] from bit-reversed source lanes; linear 16 -> 8 -> bf16 into xpad
    float pooled[16];
    #pragma unroll
    for (int c = 0; c < 16; ++c) {
        const int s = ((c & 1) << 3) | (((c >> 1) & 1) << 2) | (((c >> 2) & 1) << 1) | ((c >> 3) & 1);
        pooled[c] = __shfl(pv[0], s, 64);
    }
    if (lane < 8) {
        float r = l2b[lane];
        #pragma unroll
        for (int c = 0; c < 16; ++c) r = fmaf(pooled[c] * (1.f/128.f), l2w[c*8 + lane], r);
        xpad[(size_t)n*544 + 512 + lane] = f2bf(r);
    }
}

// ---------------- lin_w (520x256 f32, k-major) -> Bt (256x544 bf16, col-major, zero-padded) ----------------
__global__ __launch_bounds__(256) void k_prepB(const float* __restrict__ lin_w, ushort* __restrict__ Bt) {
    const int col = blockIdx.x;  // 0..255
    for (int k = threadIdx.x; k < 544; k += 256) {
        float v = (k < 520) ? lin_w[(size_t)k*256 + col] : 0.f;
        Bt[(size_t)col*544 + k] = f2bf(v);
    }
}

// ---------------- bf16-MFMA GEMM, barrier-free K-loop, direct global fragment loads ----------------
// xpad (N x 544 bf16) @ Bt^T -> xhb (N x 256 bf16) + fused al/ar.
// XCD-bijective swizzle: 4 column-siblings of a row-tile are consecutive on the same XCD -> L2 reuse.
__global__ __launch_bounds__(128) void k_gemm_mfma(
    const ushort* __restrict__ xpad, const ushort* __restrict__ Bt,
    const float* __restrict__ att_l, const float* __restrict__ att_r,
    ushort* __restrict__ xhb, float* __restrict__ al, float* __restrict__ ar, int N) {
    __shared__ __align__(16) float ep[32*68];

    const int t = threadIdx.x;
    const int wv = t >> 6, lane = t & 63;

    // bijective XCD swizzle (m204)
    const int nwg = gridDim.x;
    const int q = nwg >> 3, r = nwg & 7;
    const int xcd = blockIdx.x & 7, idx = blockIdx.x >> 3;
    const int logical = (xcd < r ? xcd*(q+1) : r*(q+1) + (xcd-r)*q) + idx;
    const int m0 = (logical >> 2) * 32;
    const int c0 = (logical & 3) * 64;

    const int frow = lane & 15;
    const int fkg  = (lane >> 4) * 8;

    const ushort* ap = &xpad[(size_t)(m0 + wv*16 + frow)*544 + fkg];
    const ushort* bp0 = &Bt[(size_t)(c0 +      frow)*544 + fkg];
    const ushort* bp1 = &Bt[(size_t)(c0 + 16 + frow)*544 + fkg];
    const ushort* bp2 = &Bt[(size_t)(c0 + 32 + frow)*544 + fkg];
    const ushort* bp3 = &Bt[(size_t)(c0 + 48 + frow)*544 + fkg];

    f32x4 acc[4];
    #pragma unroll
    for (int j = 0; j < 4; ++j) acc[j] = (f32x4)0.f;

    for (int k0 = 0; k0 < 544; k0 += 32) {
        short8 af = *reinterpret_cast<const short8*>(ap + k0);
        short8 b0 = *reinterpret_cast<const short8*>(bp0 + k0);
        short8 b1 = *reinterpret_cast<const short8*>(bp1 + k0);
        short8 b2 = *reinterpret_cast<const short8*>(bp2 + k0);
        short8 b3 = *reinterpret_cast<const short8*>(bp3 + k0);
        acc[0] = __builtin_amdgcn_mfma_f32_16x16x32_bf16(af, b0, acc[0], 0, 0, 0);
        acc[1] = __builtin_amdgcn_mfma_f32_16x16x32_bf16(af, b1, acc[1], 0, 0, 0);
        acc[2] = __builtin_amdgcn_mfma_f32_16x16x32_bf16(af, b2, acc[2], 0, 0, 0);
        acc[3] = __builtin_amdgcn_mfma_f32_16x16x32_bf16(af, b3, acc[3], 0, 0, 0);
    }

    // ---- epilogue: transpose through LDS; emit bf16 rows + fused al/ar ----
    {
        const int rb = wv*16 + (lane >> 4)*4;
        const int cb = lane & 15;
        #pragma unroll
        for (int j = 0; j < 4; ++j)
            #pragma unroll
            for (int r2 = 0; r2 < 4; ++r2)
                ep[(rb + r2)*68 + j*16 + cb] = acc[j][r2];
    }
    __syncthreads();
    {
        const int rl = t >> 2;
        const int cq = (t & 3) * 16;
        const int row = m0 + rl;
        if (row < N) {
            const float* s = &ep[rl*68 + cq];
            float vals[16];
            #pragma unroll
            for (int i = 0; i < 16; ++i) vals[i] = s[i];
            uint u[8];
            #pragma unroll
            for (int i = 0; i < 8; ++i)
                u[i] = (uint)f2bf(vals[2*i]) | ((uint)f2bf(vals[2*i+1]) << 16);
            ushort* db = &xhb[(size_t)row*256 + c0 + cq];
            *reinterpret_cast<uint4*>(db)     = make_uint4(u[0], u[1], u[2], u[3]);
            *reinterpret_cast<uint4*>(db + 8) = make_uint4(u[4], u[5], u[6], u[7]);
            float pl = 0.f, pr = 0.f;
            #pragma unroll
            for (int i = 0; i < 16; ++i) {
                pl = fmaf(vals[i], att_l[c0 + cq + i], pl);
                pr = fmaf(vals[i], att_r[c0 + cq + i], pr);
            }
            pl += __shfl_xor(pl, 1, 64);
            pr += __shfl_xor(pr, 1, 64);
            if ((t & 1) == 0) {
                const int head = (c0 >> 5) + ((t & 3) >> 1);
                al[(size_t)row*8 + head] = pl;
                ar[(size_t)row*8 + head] = pr;
            }
        }
    }
}

// ---------------- CSR build ----------------
__global__ __launch_bounds__(256) void k_deg(const int* __restrict__ dst, int* __restrict__ deg, int E) {
    int e = blockIdx.x * 256 + threadIdx.x;
    if (e < E) atomicAdd(&deg[dst[e]], 1);
}

// shuffle-based scan; zeroes deg after reading
__global__ __launch_bounds__(1024) void k_scan(int* __restrict__ deg, int* __restrict__ row_start, int N) {
    __shared__ int wsum[16];
    __shared__ int carry;
    const int t = threadIdx.x;
    const int w = t >> 6, ln = t & 63;
    if (t == 0) { carry = 0; row_start[0] = 0; }
    __syncthreads();
    for (int start = 0; start < N; start += 1024) {
        int i = start + t;
        int v = 0;
        if (i < N) { v = deg[i]; deg[i] = 0; }
        int s = v;
        #pragma unroll
        for (int d = 1; d < 64; d <<= 1) {
            int u = __shfl_up(s, d, 64);
            if (ln >= d) s += u;
        }
        if (ln == 63) wsum[w] = s;
        __syncthreads();
        if (w == 0) {
            int ws = (ln < 16) ? wsum[ln] : 0;
            int e = ws;
            #pragma unroll
            for (int d = 1; d < 16; d <<= 1) {
                int u = __shfl_up(e, d, 64);
                if (ln >= d) e += u;
            }
            if (ln < 16) wsum[ln] = e - ws;
        }
        __syncthreads();
        int incl = s + wsum[w] + carry;
        if (i < N) row_start[i + 1] = incl;
        __syncthreads();
        if (t == 1023) carry = incl;
    }
}

__global__ __launch_bounds__(256) void k_fill(
    const int* __restrict__ src, const int* __restrict__ dst,
    const int* __restrict__ row_start, int* __restrict__ cursor,
    int* __restrict__ csr, int E) {
    int e = blockIdx.x * 256 + threadIdx.x;
    if (e < E) {
        int d = dst[e];
        int p = atomicAdd(&cursor[d], 1);
        csr[row_start[d] + p] = src[e];
    }
}

// ---------------- per-dst single-pass softmax aggregation (no max-shift; unroll x2) ----------------
__global__ __launch_bounds__(256) void k_agg(
    const ushort* __restrict__ xhb,
    const float* __restrict__ al, const float* __restrict__ ar,
    const float* __restrict__ onehot, const uint* __restrict__ ohb,
    const float* __restrict__ bias,
    const int* __restrict__ row_start, const int* __restrict__ csr,
    float* __restrict__ out_x, float* __restrict__ out_oh, int N) {
    const int wave = threadIdx.x >> 6;
    const int lane = threadIdx.x & 63;
    const int n = blockIdx.x * 4 + wave;
    if (n >= N) return;
    const int h = lane >> 3;
    const float ard = ar[(size_t)n*8 + h];

    // self loop
    float a_self = al[(size_t)n*8 + h] + ard;
    a_self = (a_self > 0.f) ? a_self : NEG_SLOPE * a_self;
    float e_self = __expf(a_self);
    uint2 xsb = *reinterpret_cast<const uint2*>(&xhb[(size_t)n*256 + lane*4]);
    float4 acc;
    acc.x = e_self * bflo(xsb.x); acc.y = e_self * bfhi(xsb.x);
    acc.z = e_self * bflo(xsb.y); acc.w = e_self * bfhi(xsb.y);
    float den = e_self;
    float oh0 = 0.f, oh1 = 0.f;

    const int beg = row_start[n], end = row_start[n+1];
    int i = beg;
    for (; i + 1 < end; i += 2) {
        const int s0 = csr[i], s1 = csr[i+1];
        const float al0 = al[(size_t)s0*8 + h], al1 = al[(size_t)s1*8 + h];
        const uint2 xb0 = *reinterpret_cast<const uint2*>(&xhb[(size_t)s0*256 + lane*4]);
        const uint2 xb1 = *reinterpret_cast<const uint2*>(&xhb[(size_t)s1*256 + lane*4]);
        const uint ob0 = ohb[(size_t)s0*64 + lane];
        const uint ob1 = ohb[(size_t)s1*64 + lane];
        float a0 = al0 + ard; a0 = (a0 > 0.f) ? a0 : NEG_SLOPE * a0;
        float a1 = al1 + ard; a1 = (a1 > 0.f) ? a1 : NEG_SLOPE * a1;
        const float e0 = __expf(a0), e1 = __expf(a1);
        acc.x = fmaf(e0, bflo(xb0.x), fmaf(e1, bflo(xb1.x), acc.x));
        acc.y = fmaf(e0, bfhi(xb0.x), fmaf(e1, bfhi(xb1.x), acc.y));
        acc.z = fmaf(e0, bflo(xb0.y), fmaf(e1, bflo(xb1.y), acc.z));
        acc.w = fmaf(e0, bfhi(xb0.y), fmaf(e1, bfhi(xb1.y), acc.w));
        den += e0 + e1;
        oh0 += bflo(ob0) + bflo(ob1);
        oh1 += bfhi(ob0) + bfhi(ob1);
    }
    if (i < end) {
        const int s0 = csr[i];
        float a0 = al[(size_t)s0*8 + h] + ard;
        a0 = (a0 > 0.f) ? a0 : NEG_SLOPE * a0;
        const float e0 = __expf(a0);
        const uint2 xb0 = *reinterpret_cast<const uint2*>(&xhb[(size_t)s0*256 + lane*4]);
        const uint ob0 = ohb[(size_t)s0*64 + lane];
        acc.x = fmaf(e0, bflo(xb0.x), acc.x);
        acc.y = fmaf(e0, bfhi(xb0.x), acc.y);
        acc.z = fmaf(e0, bflo(xb0.y), acc.z);
        acc.w = fmaf(e0, bfhi(xb0.y), acc.w);
        den += e0;
        oh0 += bflo(ob0);
        oh1 += bfhi(ob0);
    }
    const float inv = 1.f / den;
    const float4 bv = *reinterpret_cast<const float4*>(&bias[lane*4]);
    float4 o;
    o.x = fmaf(acc.x, inv, bv.x);
    o.y = fmaf(acc.y, inv, bv.y);
    o.z = fmaf(acc.z, inv, bv.z);
    o.w = fmaf(acc.w, inv, bv.w);
    *reinterpret_cast<float4*>(&out_x[(size_t)n*256 + lane*4]) = o;
    float2 so = *reinterpret_cast<const float2*>(&onehot[(size_t)n*128 + lane*2]);  // self f32
    float2 oo;
    oo.x = oh0 + 2.f*so.x;
    oo.y = oh1 + 2.f*so.y;
    *reinterpret_cast<float2*>(&out_oh[(size_t)n*128 + lane*2]) = oo;
}

// ---------------- launcher ----------------
extern "C" void kernel_launch(void* const* d_in, const int* in_sizes, int n_in,
                              void* d_out, int out_size, void* d_ws, size_t ws_size,
                              hipStream_t stream) {
    const float* x      = (const float*)d_in[0];
    const float* onehot = (const float*)d_in[1];
    const int*   adj    = (const int*)d_in[2];
    const float* lin_w  = (const float*)d_in[4];
    const float* att_l  = (const float*)d_in[5];
    const float* att_r  = (const float*)d_in[6];
    const float* bias   = (const float*)d_in[7];
    const float* c1w    = (const float*)d_in[8];
    const float* c1b    = (const float*)d_in[9];
    const float* c2w    = (const float*)d_in[10];
    const float* c2b    = (const float*)d_in[11];
    const float* l2w    = (const float*)d_in[12];
    const float* l2b    = (const float*)d_in[13];

    const int N = in_sizes[0] / 512;
    const int E = in_sizes[2] / 2;
    const int* src = adj;
    const int* dst = adj + E;

    float* out_x  = (float*)d_out;
    float* out_oh = out_x + (size_t)N * 256;

    // workspace layout
    ushort* xpad     = (ushort*)d_ws;                       // N*544 bf16
    ushort* Bt       = xpad + (size_t)N * 544;              // 256*544 bf16
    ushort* xhb      = Bt + (size_t)256 * 544;              // N*256 bf16
    uint*   ohb      = (uint*)(xhb + (size_t)N * 256);      // N*64 packed bf16x2
    float*  al       = (float*)(ohb + (size_t)N * 64);      // N*8
    float*  ar       = al + (size_t)N * 8;                  // N*8
    int*   row_start = (int*)(ar + (size_t)N * 8);          // N+1
    int*   cursor    = row_start + (N + 1);                 // N
    int*   csr       = cursor + N;                          // E

    const int EB = (E + 255) / 256;
    const int NB = (N + 255) / 256;

    k_zero_int<<<NB, 256, 0, stream>>>(cursor, N);
    k_conv_wave<<<(N + 3) / 4, 256, 0, stream>>>(onehot, c1w, c1b, c2w, c2b, l2w, l2b, xpad, ohb, N);
    k_prepX<<<N, 64, 0, stream>>>(x, xpad);
    k_prepB<<<256, 256, 0, stream>>>(lin_w, Bt);
    k_deg<<<EB, 256, 0, stream>>>(dst, cursor, E);
    k_gemm_mfma<<<((N + 31) / 32) * 4, 128, 0, stream>>>(xpad, Bt, att_l, att_r, xhb, al, ar, N);
    k_scan<<<1, 1024, 0, stream>>>(cursor, row_start, N);
    k_fill<<<EB, 256, 0, stream>>>(src, dst, row_start, cursor, csr, E);
    k_agg<<<(N + 3) / 4, 256, 0, stream>>>(xhb, al, ar, onehot, ohb, bias, row_start, csr, out_x, out_oh, N);
}

// Round 10
// 180.384 us; speedup vs baseline: 1.0859x; 1.0859x over previous
//
#include <hip/hip_runtime.h>

#define NEG_SLOPE 0.2f

typedef __attribute__((ext_vector_type(4))) float f32x4;
typedef __attribute__((ext_vector_type(2))) float f32x2;
typedef __attribute__((ext_vector_type(8))) short short8;

__device__ __forceinline__ f32x2 mk2(float a, float b) { f32x2 r; r[0] = a; r[1] = b; return r; }

__device__ __forceinline__ f32x2 FMA2(f32x2 a, f32x2 b, f32x2 c) {
#if __has_builtin(__builtin_elementwise_fma)
    return __builtin_elementwise_fma(a, b, c);
#else
    f32x2 r; r[0] = fmaf(a[0], b[0], c[0]); r[1] = fmaf(a[1], b[1], c[1]); return r;
#endif
}

__device__ __forceinline__ ushort f2bf(float f) {
    uint u = __float_as_uint(f);
    u += 0x7FFFu + ((u >> 16) & 1u);
    return (ushort)(u >> 16);
}
__device__ __forceinline__ float bflo(uint u) { return __uint_as_float(u << 16); }
__device__ __forceinline__ float bfhi(uint u) { return __uint_as_float(u & 0xffff0000u); }

// ---------------- conv pipe + x->bf16 prep + cursor zero, wave-per-node ----------------
__global__ __launch_bounds__(256) void k_conv_wave(
    const float* __restrict__ x, const float* __restrict__ onehot,
    const float* __restrict__ c1w, const float* __restrict__ c1b,
    const float* __restrict__ c2w, const float* __restrict__ c2b,
    const float* __restrict__ l2w, const float* __restrict__ l2b,
    ushort* __restrict__ xpad, uint* __restrict__ ohb, int* __restrict__ cursor, int N) {
    // fused: zero cursor (completes before k_prep's atomics via stream order)
    const int gid = blockIdx.x * 256 + threadIdx.x;
    if (gid < N) cursor[gid] = 0;

    const int wave = threadIdx.x >> 6;
    const int lane = threadIdx.x & 63;
    const int n = blockIdx.x * 4 + wave;
    if (n >= N) return;

    // fused prepX: x row f32 -> xpad bf16 cols 0..511 (+ zero pad 520..543)
    {
        const float* xp = &x[(size_t)n*512 + lane*8];
        float4 lo = *reinterpret_cast<const float4*>(xp);
        float4 hi = *reinterpret_cast<const float4*>(xp + 4);
        uint4 w;
        w.x = (uint)f2bf(lo.x) | ((uint)f2bf(lo.y) << 16);
        w.y = (uint)f2bf(lo.z) | ((uint)f2bf(lo.w) << 16);
        w.z = (uint)f2bf(hi.x) | ((uint)f2bf(hi.y) << 16);
        w.w = (uint)f2bf(hi.z) | ((uint)f2bf(hi.w) << 16);
        *reinterpret_cast<uint4*>(&xpad[(size_t)n*544 + lane*8]) = w;
        if (lane < 3) {
            const uint4 z = make_uint4(0,0,0,0);
            *reinterpret_cast<uint4*>(&xpad[(size_t)n*544 + 520 + lane*8]) = z;
        }
    }

    float2 in2 = *reinterpret_cast<const float2*>(&onehot[(size_t)n * 128 + lane * 2]);
    ohb[(size_t)n*64 + lane] = (uint)f2bf(in2.x) | ((uint)f2bf(in2.y) << 16);
    float v0 = log1pf(in2.x);
    float v1 = log1pf(in2.y);

    // bitonic sort of 128 elements, i = 2*lane + r; fully in registers
    #pragma unroll
    for (int k = 2; k <= 128; k <<= 1) {
        const bool asc = ((lane & (k >> 1)) == 0);
        #pragma unroll
        for (int j = k >> 1; j >= 2; j >>= 1) {
            const int m = j >> 1;
            float p0 = __shfl_xor(v0, m, 64);
            float p1 = __shfl_xor(v1, m, 64);
            const bool keepmin = (((lane & m) == 0) == asc);
            v0 = keepmin ? fminf(v0, p0) : fmaxf(v0, p0);
            v1 = keepmin ? fminf(v1, p1) : fmaxf(v1, p1);
        }
        float lo = fminf(v0, v1), hi = fmaxf(v0, v1);
        v0 = asc ? lo : hi;
        v1 = asc ? hi : lo;
    }

    float pm = __shfl_up(v1, 1, 64); if (lane == 0)  pm = 0.f;
    float pp = __shfl_down(v0, 1, 64); if (lane == 63) pp = 0.f;

    // conv1: 1->8, packed over the lane's two positions
    float h0[8], h1[8];
    {
        const f32x2 xm = mk2(pm, v0), x0 = mk2(v0, v1), xp2 = mk2(v1, pp);
        #pragma unroll
        for (int c = 0; c < 8; ++c) {
            const float w0 = c1w[c*3+0], w1 = c1w[c*3+1], w2 = c1w[c*3+2], b = c1b[c];
            f32x2 h = FMA2(xm, mk2(w0, w0), FMA2(x0, mk2(w1, w1), FMA2(xp2, mk2(w2, w2), mk2(b, b))));
            h0[c] = fmaxf(h[0], 0.f);
            h1[c] = fmaxf(h[1], 0.f);
        }
    }

    // conv2: 8->16, packed
    f32x2 a01[16];
    #pragma unroll
    for (int c = 0; c < 16; ++c) { float b = c2b[c]; a01[c] = mk2(b, b); }
    #pragma unroll
    for (int ci = 0; ci < 8; ++ci) {
        float hm = __shfl_up(h1[ci], 1, 64); if (lane == 0)  hm = 0.f;
        float hp = __shfl_down(h0[ci], 1, 64); if (lane == 63) hp = 0.f;
        const f32x2 xm = mk2(hm, h0[ci]), x0 = mk2(h0[ci], h1[ci]), xp2 = mk2(h1[ci], hp);
        #pragma unroll
        for (int c = 0; c < 16; ++c) {
            const float w0 = c2w[(c*8+ci)*3+0], w1 = c2w[(c*8+ci)*3+1], w2 = c2w[(c*8+ci)*3+2];
            a01[c] = FMA2(xm, mk2(w0, w0), FMA2(x0, mk2(w1, w1), FMA2(xp2, mk2(w2, w2), a01[c])));
        }
    }

    // relu + in-lane pair sum
    float pv[16];
    #pragma unroll
    for (int c = 0; c < 16; ++c) pv[c] = fmaxf(a01[c][0], 0.f) + fmaxf(a01[c][1], 0.f);

    // channel-splitting tree reduction: 17 shuffles total.
    {
        const bool up1 = lane & 1;
        #pragma unroll
        for (int j = 0; j < 8; ++j) {
            float send = up1 ? pv[j] : pv[j+8];
            float keep = up1 ? pv[j+8] : pv[j];
            pv[j] = keep + __shfl_xor(send, 1, 64);
        }
        const bool up2 = (lane >> 1) & 1;
        #pragma unroll
        for (int j = 0; j < 4; ++j) {
            float send = up2 ? pv[j] : pv[j+4];
            float keep = up2 ? pv[j+4] : pv[j];
            pv[j] = keep + __shfl_xor(send, 2, 64);
        }
        const bool up3 = (lane >> 2) & 1;
        #pragma unroll
        for (int j = 0; j < 2; ++j) {
            float send = up3 ? pv[j] : pv[j+2];
            float keep = up3 ? pv[j+2] : pv[j];
            pv[j] = keep + __shfl_xor(send, 4, 64);
        }
        const bool up4 = (lane >> 3) & 1;
        {
            float send = up4 ? pv[0] : pv[1];
            float keep = up4 ? pv[1] : pv[0];
            pv[0] = keep + __shfl_xor(send, 8, 64);
        }
        pv[0] += __shfl_xor(pv[0], 16, 64);
        pv[0] += __shfl_xor(pv[0], 32, 64);
    }

    // gather pooled[c] from bit-reversed source lanes; linear 16 -> 8 -> bf16 into xpad
    float pooled[16];
    #pragma unroll
    for (int c = 0; c < 16; ++c) {
        const int s = ((c & 1) << 3) | (((c >> 1) & 1) << 2) | (((c >> 2) & 1) << 1) | ((c >> 3) & 1);
        pooled[c] = __shfl(pv[0], s, 64);
    }
    if (lane < 8) {
        float r = l2b[lane];
        #pragma unroll
        for (int c = 0; c < 16; ++c) r = fmaf(pooled[c] * (1.f/128.f), l2w[c*8 + lane], r);
        xpad[(size_t)n*544 + 512 + lane] = f2bf(r);
    }
}

// ---------------- fused: lin_w -> Bt (blocks 0..255) + degree count (all blocks) ----------------
__global__ __launch_bounds__(256) void k_prep(
    const float* __restrict__ lin_w, ushort* __restrict__ Bt,
    const int* __restrict__ dst, int* __restrict__ cursor, int E) {
    const int gid = blockIdx.x * 256 + threadIdx.x;
    if (gid < E) atomicAdd(&cursor[dst[gid]], 1);
    const int col = blockIdx.x;
    if (col < 256) {
        for (int k = threadIdx.x; k < 544; k += 256) {
            float v = (k < 520) ? lin_w[(size_t)k*256 + col] : 0.f;
            Bt[(size_t)col*544 + k] = f2bf(v);
        }
    }
}

// ---------------- bf16-MFMA GEMM, barrier-free K-loop, direct global fragment loads ----------------
__global__ __launch_bounds__(128) void k_gemm_mfma(
    const ushort* __restrict__ xpad, const ushort* __restrict__ Bt,
    const float* __restrict__ att_l, const float* __restrict__ att_r,
    ushort* __restrict__ xhb, float* __restrict__ al, float* __restrict__ ar, int N) {
    __shared__ __align__(16) float ep[32*68];

    const int t = threadIdx.x;
    const int wv = t >> 6, lane = t & 63;

    // bijective XCD swizzle (m204)
    const int nwg = gridDim.x;
    const int q = nwg >> 3, r = nwg & 7;
    const int xcd = blockIdx.x & 7, idx = blockIdx.x >> 3;
    const int logical = (xcd < r ? xcd*(q+1) : r*(q+1) + (xcd-r)*q) + idx;
    const int m0 = (logical >> 2) * 32;
    const int c0 = (logical & 3) * 64;

    const int frow = lane & 15;
    const int fkg  = (lane >> 4) * 8;

    const ushort* ap = &xpad[(size_t)(m0 + wv*16 + frow)*544 + fkg];
    const ushort* bp0 = &Bt[(size_t)(c0 +      frow)*544 + fkg];
    const ushort* bp1 = &Bt[(size_t)(c0 + 16 + frow)*544 + fkg];
    const ushort* bp2 = &Bt[(size_t)(c0 + 32 + frow)*544 + fkg];
    const ushort* bp3 = &Bt[(size_t)(c0 + 48 + frow)*544 + fkg];

    f32x4 acc[4];
    #pragma unroll
    for (int j = 0; j < 4; ++j) acc[j] = (f32x4)0.f;

    for (int k0 = 0; k0 < 544; k0 += 32) {
        short8 af = *reinterpret_cast<const short8*>(ap + k0);
        short8 b0 = *reinterpret_cast<const short8*>(bp0 + k0);
        short8 b1 = *reinterpret_cast<const short8*>(bp1 + k0);
        short8 b2 = *reinterpret_cast<const short8*>(bp2 + k0);
        short8 b3 = *reinterpret_cast<const short8*>(bp3 + k0);
        acc[0] = __builtin_amdgcn_mfma_f32_16x16x32_bf16(af, b0, acc[0], 0, 0, 0);
        acc[1] = __builtin_amdgcn_mfma_f32_16x16x32_bf16(af, b1, acc[1], 0, 0, 0);
        acc[2] = __builtin_amdgcn_mfma_f32_16x16x32_bf16(af, b2, acc[2], 0, 0, 0);
        acc[3] = __builtin_amdgcn_mfma_f32_16x16x32_bf16(af, b3, acc[3], 0, 0, 0);
    }

    // ---- epilogue: transpose through LDS; emit bf16 rows + fused al/ar ----
    {
        const int rb = wv*16 + (lane >> 4)*4;
        const int cb = lane & 15;
        #pragma unroll
        for (int j = 0; j < 4; ++j)
            #pragma unroll
            for (int r2 = 0; r2 < 4; ++r2)
                ep[(rb + r2)*68 + j*16 + cb] = acc[j][r2];
    }
    __syncthreads();
    {
        const int rl = t >> 2;
        const int cq = (t & 3) * 16;
        const int row = m0 + rl;
        if (row < N) {
            const float* s = &ep[rl*68 + cq];
            float vals[16];
            #pragma unroll
            for (int i = 0; i < 16; ++i) vals[i] = s[i];
            uint u[8];
            #pragma unroll
            for (int i = 0; i < 8; ++i)
                u[i] = (uint)f2bf(vals[2*i]) | ((uint)f2bf(vals[2*i+1]) << 16);
            ushort* db = &xhb[(size_t)row*256 + c0 + cq];
            *reinterpret_cast<uint4*>(db)     = make_uint4(u[0], u[1], u[2], u[3]);
            *reinterpret_cast<uint4*>(db + 8) = make_uint4(u[4], u[5], u[6], u[7]);
            float pl = 0.f, pr = 0.f;
            #pragma unroll
            for (int i = 0; i < 16; ++i) {
                pl = fmaf(vals[i], att_l[c0 + cq + i], pl);
                pr = fmaf(vals[i], att_r[c0 + cq + i], pr);
            }
            pl += __shfl_xor(pl, 1, 64);
            pr += __shfl_xor(pr, 1, 64);
            if ((t & 1) == 0) {
                const int head = (c0 >> 5) + ((t & 3) >> 1);
                al[(size_t)row*8 + head] = pl;
                ar[(size_t)row*8 + head] = pr;
            }
        }
    }
}

// ---------------- shuffle-based scan; zeroes deg after reading ----------------
__global__ __launch_bounds__(1024) void k_scan(int* __restrict__ deg, int* __restrict__ row_start, int N) {
    __shared__ int wsum[16];
    __shared__ int carry;
    const int t = threadIdx.x;
    const int w = t >> 6, ln = t & 63;
    if (t == 0) { carry = 0; row_start[0] = 0; }
    __syncthreads();
    for (int start = 0; start < N; start += 1024) {
        int i = start + t;
        int v = 0;
        if (i < N) { v = deg[i]; deg[i] = 0; }
        int s = v;
        #pragma unroll
        for (int d = 1; d < 64; d <<= 1) {
            int u = __shfl_up(s, d, 64);
            if (ln >= d) s += u;
        }
        if (ln == 63) wsum[w] = s;
        __syncthreads();
        if (w == 0) {
            int ws = (ln < 16) ? wsum[ln] : 0;
            int e = ws;
            #pragma unroll
            for (int d = 1; d < 16; d <<= 1) {
                int u = __shfl_up(e, d, 64);
                if (ln >= d) e += u;
            }
            if (ln < 16) wsum[ln] = e - ws;
        }
        __syncthreads();
        int incl = s + wsum[w] + carry;
        if (i < N) row_start[i + 1] = incl;
        __syncthreads();
        if (t == 1023) carry = incl;
    }
}

__global__ __launch_bounds__(256) void k_fill(
    const int* __restrict__ src, const int* __restrict__ dst,
    const int* __restrict__ row_start, int* __restrict__ cursor,
    int* __restrict__ csr, int E) {
    int e = blockIdx.x * 256 + threadIdx.x;
    if (e < E) {
        int d = dst[e];
        int p = atomicAdd(&cursor[d], 1);
        csr[row_start[d] + p] = src[e];
    }
}

// ---------------- per-dst single-pass softmax aggregation (no max-shift; unroll x4) ----------------
__global__ __launch_bounds__(256) void k_agg(
    const ushort* __restrict__ xhb,
    const float* __restrict__ al, const float* __restrict__ ar,
    const float* __restrict__ onehot, const uint* __restrict__ ohb,
    const float* __restrict__ bias,
    const int* __restrict__ row_start, const int* __restrict__ csr,
    float* __restrict__ out_x, float* __restrict__ out_oh, int N) {
    const int wave = threadIdx.x >> 6;
    const int lane = threadIdx.x & 63;
    const int n = blockIdx.x * 4 + wave;
    if (n >= N) return;
    const int h = lane >> 3;
    const float ard = ar[(size_t)n*8 + h];

    // self loop
    float a_self = al[(size_t)n*8 + h] + ard;
    a_self = fmaxf(a_self, NEG_SLOPE * a_self);
    float e_self = __expf(a_self);
    uint2 xsb = *reinterpret_cast<const uint2*>(&xhb[(size_t)n*256 + lane*4]);
    float4 acc;
    acc.x = e_self * bflo(xsb.x); acc.y = e_self * bfhi(xsb.x);
    acc.z = e_self * bflo(xsb.y); acc.w = e_self * bfhi(xsb.y);
    float den = e_self;
    float oh0 = 0.f, oh1 = 0.f;

    const int beg = row_start[n], end = row_start[n+1];
    int i = beg;
    for (; i + 3 < end; i += 4) {
        const int s0 = csr[i], s1 = csr[i+1], s2 = csr[i+2], s3 = csr[i+3];
        const float al0 = al[(size_t)s0*8 + h], al1 = al[(size_t)s1*8 + h];
        const float al2 = al[(size_t)s2*8 + h], al3 = al[(size_t)s3*8 + h];
        const uint2 xb0 = *reinterpret_cast<const uint2*>(&xhb[(size_t)s0*256 + lane*4]);
        const uint2 xb1 = *reinterpret_cast<const uint2*>(&xhb[(size_t)s1*256 + lane*4]);
        const uint2 xb2 = *reinterpret_cast<const uint2*>(&xhb[(size_t)s2*256 + lane*4]);
        const uint2 xb3 = *reinterpret_cast<const uint2*>(&xhb[(size_t)s3*256 + lane*4]);
        const uint ob0 = ohb[(size_t)s0*64 + lane];
        const uint ob1 = ohb[(size_t)s1*64 + lane];
        const uint ob2 = ohb[(size_t)s2*64 + lane];
        const uint ob3 = ohb[(size_t)s3*64 + lane];
        float a0 = al0 + ard; a0 = fmaxf(a0, NEG_SLOPE * a0);
        float a1 = al1 + ard; a1 = fmaxf(a1, NEG_SLOPE * a1);
        float a2 = al2 + ard; a2 = fmaxf(a2, NEG_SLOPE * a2);
        float a3 = al3 + ard; a3 = fmaxf(a3, NEG_SLOPE * a3);
        const float e0 = __expf(a0), e1 = __expf(a1), e2 = __expf(a2), e3 = __expf(a3);
        acc.x = fmaf(e0, bflo(xb0.x), fmaf(e1, bflo(xb1.x), fmaf(e2, bflo(xb2.x), fmaf(e3, bflo(xb3.x), acc.x))));
        acc.y = fmaf(e0, bfhi(xb0.x), fmaf(e1, bfhi(xb1.x), fmaf(e2, bfhi(xb2.x), fmaf(e3, bfhi(xb3.x), acc.y))));
        acc.z = fmaf(e0, bflo(xb0.y), fmaf(e1, bflo(xb1.y), fmaf(e2, bflo(xb2.y), fmaf(e3, bflo(xb3.y), acc.z))));
        acc.w = fmaf(e0, bfhi(xb0.y), fmaf(e1, bfhi(xb1.y), fmaf(e2, bfhi(xb2.y), fmaf(e3, bfhi(xb3.y), acc.w))));
        den += (e0 + e1) + (e2 + e3);
        oh0 += (bflo(ob0) + bflo(ob1)) + (bflo(ob2) + bflo(ob3));
        oh1 += (bfhi(ob0) + bfhi(ob1)) + (bfhi(ob2) + bfhi(ob3));
    }
    for (; i < end; ++i) {
        const int s0 = csr[i];
        float a0 = al[(size_t)s0*8 + h] + ard;
        a0 = fmaxf(a0, NEG_SLOPE * a0);
        const float e0 = __expf(a0);
        const uint2 xb0 = *reinterpret_cast<const uint2*>(&xhb[(size_t)s0*256 + lane*4]);
        const uint ob0 = ohb[(size_t)s0*64 + lane];
        acc.x = fmaf(e0, bflo(xb0.x), acc.x);
        acc.y = fmaf(e0, bfhi(xb0.x), acc.y);
        acc.z = fmaf(e0, bflo(xb0.y), acc.z);
        acc.w = fmaf(e0, bfhi(xb0.y), acc.w);
        den += e0;
        oh0 += bflo(ob0);
        oh1 += bfhi(ob0);
    }
    const float inv = 1.f / den;
    const float4 bv = *reinterpret_cast<const float4*>(&bias[lane*4]);
    float4 o;
    o.x = fmaf(acc.x, inv, bv.x);
    o.y = fmaf(acc.y, inv, bv.y);
    o.z = fmaf(acc.z, inv, bv.z);
    o.w = fmaf(acc.w, inv, bv.w);
    *reinterpret_cast<float4*>(&out_x[(size_t)n*256 + lane*4]) = o;
    float2 so = *reinterpret_cast<const float2*>(&onehot[(size_t)n*128 + lane*2]);  // self f32
    float2 oo;
    oo.x = oh0 + 2.f*so.x;
    oo.y = oh1 + 2.f*so.y;
    *reinterpret_cast<float2*>(&out_oh[(size_t)n*128 + lane*2]) = oo;
}

// ---------------- launcher ----------------
extern "C" void kernel_launch(void* const* d_in, const int* in_sizes, int n_in,
                              void* d_out, int out_size, void* d_ws, size_t ws_size,
                              hipStream_t stream) {
    const float* x      = (const float*)d_in[0];
    const float* onehot = (const float*)d_in[1];
    const int*   adj    = (const int*)d_in[2];
    const float* lin_w  = (const float*)d_in[4];
    const float* att_l  = (const float*)d_in[5];
    const float* att_r  = (const float*)d_in[6];
    const float* bias   = (const float*)d_in[7];
    const float* c1w    = (const float*)d_in[8];
    const float* c1b    = (const float*)d_in[9];
    const float* c2w    = (const float*)d_in[10];
    const float* c2b    = (const float*)d_in[11];
    const float* l2w    = (const float*)d_in[12];
    const float* l2b    = (const float*)d_in[13];

    const int N = in_sizes[0] / 512;
    const int E = in_sizes[2] / 2;
    const int* src = adj;
    const int* dst = adj + E;

    float* out_x  = (float*)d_out;
    float* out_oh = out_x + (size_t)N * 256;

    // workspace layout
    ushort* xpad     = (ushort*)d_ws;                       // N*544 bf16
    ushort* Bt       = xpad + (size_t)N * 544;              // 256*544 bf16
    ushort* xhb      = Bt + (size_t)256 * 544;              // N*256 bf16
    uint*   ohb      = (uint*)(xhb + (size_t)N * 256);      // N*64 packed bf16x2
    float*  al       = (float*)(ohb + (size_t)N * 64);      // N*8
    float*  ar       = al + (size_t)N * 8;                  // N*8
    int*   row_start = (int*)(ar + (size_t)N * 8);          // N+1
    int*   cursor    = row_start + (N + 1);                 // N
    int*   csr       = cursor + N;                          // E

    const int EB = (E + 255) / 256;

    k_conv_wave<<<(N + 3) / 4, 256, 0, stream>>>(x, onehot, c1w, c1b, c2w, c2b, l2w, l2b, xpad, ohb, cursor, N);
    k_prep<<<EB, 256, 0, stream>>>(lin_w, Bt, dst, cursor, E);
    k_gemm_mfma<<<((N + 31) / 32) * 4, 128, 0, stream>>>(xpad, Bt, att_l, att_r, xhb, al, ar, N);
    k_scan<<<1, 1024, 0, stream>>>(cursor, row_start, N);
    k_fill<<<EB, 256, 0, stream>>>(src, dst, row_start, cursor, csr, E);
    k_agg<<<(N + 3) / 4, 256, 0, stream>>>(xhb, al, ar, onehot, ohb, bias, row_start, csr, out_x, out_oh, N);
}

// Round 11
// 177.403 us; speedup vs baseline: 1.1042x; 1.0168x over previous
//
#include <hip/hip_runtime.h>

#define NEG_SLOPE 0.2f

typedef __attribute__((ext_vector_type(4))) float f32x4;
typedef __attribute__((ext_vector_type(2))) float f32x2;
typedef __attribute__((ext_vector_type(8))) short short8;

__device__ __forceinline__ f32x2 mk2(float a, float b) { f32x2 r; r[0] = a; r[1] = b; return r; }

__device__ __forceinline__ f32x2 FMA2(f32x2 a, f32x2 b, f32x2 c) {
#if __has_builtin(__builtin_elementwise_fma)
    return __builtin_elementwise_fma(a, b, c);
#else
    f32x2 r; r[0] = fmaf(a[0], b[0], c[0]); r[1] = fmaf(a[1], b[1], c[1]); return r;
#endif
}

__device__ __forceinline__ ushort f2bf(float f) {
    uint u = __float_as_uint(f);
    u += 0x7FFFu + ((u >> 16) & 1u);
    return (ushort)(u >> 16);
}
__device__ __forceinline__ float bflo(uint u) { return __uint_as_float(u << 16); }
__device__ __forceinline__ float bfhi(uint u) { return __uint_as_float(u & 0xffff0000u); }

// ---------------- conv pipe (conv2 via MFMA) + x->bf16 prep + cursor zero, wave-per-node ----------------
// LDS H layout per wave: logical rows 0..130 (row = pos+1, pos -1..129), 8 bf16 channels = 16B/row.
// Slot interleave: slot(row) = (row>>1) + (row&1)*66 -> writes (rows 2l+1, 2l+2) and reads both conflict-free.
__global__ __launch_bounds__(256) void k_conv_wave(
    const float* __restrict__ x, const float* __restrict__ onehot,
    const float* __restrict__ c1w, const float* __restrict__ c1b,
    const float* __restrict__ c2w, const float* __restrict__ c2b,
    const float* __restrict__ l2w, const float* __restrict__ l2b,
    ushort* __restrict__ xpad, uint* __restrict__ ohb, int* __restrict__ cursor, int N) {
    __shared__ ushort Hall[4][1056];

    // fused: zero cursor (completes before k_prep's atomics via stream order)
    const int gid = blockIdx.x * 256 + threadIdx.x;
    if (gid < N) cursor[gid] = 0;

    const int wave = threadIdx.x >> 6;
    const int lane = threadIdx.x & 63;
    const int n = blockIdx.x * 4 + wave;
    if (n >= N) return;
    ushort* H = Hall[wave];

    // fused prepX: x row f32 -> xpad bf16 cols 0..511 (+ zero pad 520..543)
    {
        const float* xp = &x[(size_t)n*512 + lane*8];
        float4 lo = *reinterpret_cast<const float4*>(xp);
        float4 hi = *reinterpret_cast<const float4*>(xp + 4);
        uint4 w;
        w.x = (uint)f2bf(lo.x) | ((uint)f2bf(lo.y) << 16);
        w.y = (uint)f2bf(lo.z) | ((uint)f2bf(lo.w) << 16);
        w.z = (uint)f2bf(hi.x) | ((uint)f2bf(hi.y) << 16);
        w.w = (uint)f2bf(hi.z) | ((uint)f2bf(hi.w) << 16);
        *reinterpret_cast<uint4*>(&xpad[(size_t)n*544 + lane*8]) = w;
        if (lane < 3) {
            const uint4 z = make_uint4(0,0,0,0);
            *reinterpret_cast<uint4*>(&xpad[(size_t)n*544 + 520 + lane*8]) = z;
        }
    }

    float2 in2 = *reinterpret_cast<const float2*>(&onehot[(size_t)n * 128 + lane * 2]);
    ohb[(size_t)n*64 + lane] = (uint)f2bf(in2.x) | ((uint)f2bf(in2.y) << 16);
    float v0 = log1pf(in2.x);
    float v1 = log1pf(in2.y);

    // bitonic sort of 128 elements, i = 2*lane + r; fully in registers
    #pragma unroll
    for (int k = 2; k <= 128; k <<= 1) {
        const bool asc = ((lane & (k >> 1)) == 0);
        #pragma unroll
        for (int j = k >> 1; j >= 2; j >>= 1) {
            const int m = j >> 1;
            float p0 = __shfl_xor(v0, m, 64);
            float p1 = __shfl_xor(v1, m, 64);
            const bool keepmin = (((lane & m) == 0) == asc);
            v0 = keepmin ? fminf(v0, p0) : fmaxf(v0, p0);
            v1 = keepmin ? fminf(v1, p1) : fmaxf(v1, p1);
        }
        float lo = fminf(v0, v1), hi = fmaxf(v0, v1);
        v0 = asc ? lo : hi;
        v1 = asc ? hi : lo;
    }

    float pm = __shfl_up(v1, 1, 64); if (lane == 0)  pm = 0.f;
    float pp = __shfl_down(v0, 1, 64); if (lane == 63) pp = 0.f;

    // conv1: 1->8, packed over the lane's two positions (f32)
    float h0[8], h1[8];
    {
        const f32x2 xm = mk2(pm, v0), x0 = mk2(v0, v1), xp2 = mk2(v1, pp);
        #pragma unroll
        for (int c = 0; c < 8; ++c) {
            const float w0 = c1w[c*3+0], w1 = c1w[c*3+1], w2 = c1w[c*3+2], b = c1b[c];
            f32x2 h = FMA2(xm, mk2(w0, w0), FMA2(x0, mk2(w1, w1), FMA2(xp2, mk2(w2, w2), mk2(b, b))));
            h0[c] = fmaxf(h[0], 0.f);
            h1[c] = fmaxf(h[1], 0.f);
        }
    }

    // stage h (bf16) into LDS rows; zero boundary rows 0 (pos -1), 129 (pos 128), 130 (g=3 pad)
    {
        if (lane == 0) {
            const uint4 z = make_uint4(0,0,0,0);
            *reinterpret_cast<uint4*>(&H[0*8])   = z;   // slot(row 0)   = 0
            *reinterpret_cast<uint4*>(&H[130*8]) = z;   // slot(row 129) = 64+66 = 130
            *reinterpret_cast<uint4*>(&H[65*8])  = z;   // slot(row 130) = 65
        }
        uint4 w0, w1;
        w0.x = (uint)f2bf(h0[0]) | ((uint)f2bf(h0[1]) << 16);
        w0.y = (uint)f2bf(h0[2]) | ((uint)f2bf(h0[3]) << 16);
        w0.z = (uint)f2bf(h0[4]) | ((uint)f2bf(h0[5]) << 16);
        w0.w = (uint)f2bf(h0[6]) | ((uint)f2bf(h0[7]) << 16);
        w1.x = (uint)f2bf(h1[0]) | ((uint)f2bf(h1[1]) << 16);
        w1.y = (uint)f2bf(h1[2]) | ((uint)f2bf(h1[3]) << 16);
        w1.z = (uint)f2bf(h1[4]) | ((uint)f2bf(h1[5]) << 16);
        w1.w = (uint)f2bf(h1[6]) | ((uint)f2bf(h1[7]) << 16);
        // pos 2*lane   -> row 2l+1 (odd)  -> slot 66+l
        // pos 2*lane+1 -> row 2l+2 (even) -> slot l+1
        *reinterpret_cast<uint4*>(&H[(66 + lane)*8]) = w1 /*placeholder*/;
        // NOTE: row 2l+1 holds pos 2l -> that's h0; row 2l+2 holds pos 2l+1 -> h1.
        *reinterpret_cast<uint4*>(&H[(66 + lane)*8]) = w0;
        *reinterpret_cast<uint4*>(&H[(lane + 1)*8])  = w1;
    }

    // conv2 as MFMA: D[pos][co] = sum_k A[pos][k] * B[k][co], k = tap*8 + ci (24 used, 32 padded)
    const int co = lane & 15;
    const int g2 = lane >> 4;
    short8 bfrag;
    #pragma unroll
    for (int j = 0; j < 8; ++j) bfrag[j] = 0;
    if (g2 < 3) {
        #pragma unroll
        for (int j = 0; j < 8; ++j) bfrag[j] = (short)f2bf(c2w[(co*8 + j)*3 + g2]);
    }
    const float bias_c = c2b[co];
    const f32x4 zacc = (f32x4)0.f;

    float poolv = 0.f;
    #pragma unroll
    for (int s = 0; s < 8; ++s) {
        const int q = s*16 + co + g2;                 // logical row = pos + g2 - 1 + 1
        const int slot = (q >> 1) + (q & 1)*66;
        short8 afrag = *reinterpret_cast<const short8*>(&H[slot*8]);
        f32x4 d = __builtin_amdgcn_mfma_f32_16x16x32_bf16(afrag, bfrag, zacc, 0, 0, 0);
        poolv += fmaxf(d[0] + bias_c, 0.f);
        poolv += fmaxf(d[1] + bias_c, 0.f);
        poolv += fmaxf(d[2] + bias_c, 0.f);
        poolv += fmaxf(d[3] + bias_c, 0.f);
    }
    // reduce over the 4 lane-groups sharing channel co
    poolv += __shfl_xor(poolv, 16, 64);
    poolv += __shfl_xor(poolv, 32, 64);

    // linear 16 -> 8 (gather pooled[c] from lane c)
    float r = (lane < 8) ? l2b[lane] : 0.f;
    #pragma unroll
    for (int c = 0; c < 16; ++c) {
        float pc = __shfl(poolv, c, 64);
        if (lane < 8) r = fmaf(pc * (1.f/128.f), l2w[c*8 + lane], r);
    }
    if (lane < 8) xpad[(size_t)n*544 + 512 + lane] = f2bf(r);
}

// ---------------- fused: lin_w -> Bt (blocks 0..255) + degree count (all blocks) ----------------
__global__ __launch_bounds__(256) void k_prep(
    const float* __restrict__ lin_w, ushort* __restrict__ Bt,
    const int* __restrict__ dst, int* __restrict__ cursor, int E) {
    const int gid = blockIdx.x * 256 + threadIdx.x;
    if (gid < E) atomicAdd(&cursor[dst[gid]], 1);
    const int col = blockIdx.x;
    if (col < 256) {
        for (int k = threadIdx.x; k < 544; k += 256) {
            float v = (k < 520) ? lin_w[(size_t)k*256 + col] : 0.f;
            Bt[(size_t)col*544 + k] = f2bf(v);
        }
    }
}

// ---------------- single-pass block scan: 20 elems/thread, 2 barriers; zeroes deg ----------------
__global__ __launch_bounds__(1024) void k_scan(int* __restrict__ deg, int* __restrict__ row_start, int N) {
    __shared__ int wsum[16];
    const int t = threadIdx.x;
    const int w = t >> 6, ln = t & 63;
    const int base = t * 20;
    int v[20];
    int run = 0;
    #pragma unroll
    for (int i = 0; i < 20; ++i) {
        const int idx = base + i;
        int d = 0;
        if (idx < N) { d = deg[idx]; deg[idx] = 0; }
        run += d;
        v[i] = run;
    }
    int s = run;
    #pragma unroll
    for (int d = 1; d < 64; d <<= 1) {
        int u = __shfl_up(s, d, 64);
        if (ln >= d) s += u;
    }
    if (ln == 63) wsum[w] = s;
    __syncthreads();
    if (w == 0) {
        int ws = (ln < 16) ? wsum[ln] : 0;
        int e2 = ws;
        #pragma unroll
        for (int d = 1; d < 16; d <<= 1) {
            int u = __shfl_up(e2, d, 64);
            if (ln >= d) e2 += u;
        }
        if (ln < 16) wsum[ln] = e2 - ws;   // exclusive wave offsets
    }
    __syncthreads();
    const int off = (s - run) + wsum[w];
    if (t == 0) row_start[0] = 0;
    #pragma unroll
    for (int i = 0; i < 20; ++i) {
        const int idx = base + i;
        if (idx < N) row_start[idx + 1] = off + v[i];
    }
}

// ---------------- bf16-MFMA GEMM + fused CSR fill ----------------
// grid = (N/32)*4 blocks x 128 thr; fill covers grid*128 edges (== E for this problem shape).
__global__ __launch_bounds__(128) void k_gemm_mfma(
    const ushort* __restrict__ xpad, const ushort* __restrict__ Bt,
    const float* __restrict__ att_l, const float* __restrict__ att_r,
    ushort* __restrict__ xhb, float* __restrict__ al, float* __restrict__ ar,
    const int* __restrict__ src, const int* __restrict__ dst,
    const int* __restrict__ row_start, int* __restrict__ cursor, int* __restrict__ csr,
    int N, int E) {
    __shared__ __align__(16) float ep[32*68];

    const int t = threadIdx.x;
    const int wv = t >> 6, lane = t & 63;

    // fused CSR fill (raw block order)
    {
        const int e = blockIdx.x * 128 + t;
        if (e < E) {
            const int d = dst[e];
            const int p = atomicAdd(&cursor[d], 1);
            csr[row_start[d] + p] = src[e];
        }
    }

    // bijective XCD swizzle (m204)
    const int nwg = gridDim.x;
    const int q = nwg >> 3, r = nwg & 7;
    const int xcd = blockIdx.x & 7, idx = blockIdx.x >> 3;
    const int logical = (xcd < r ? xcd*(q+1) : r*(q+1) + (xcd-r)*q) + idx;
    const int m0 = (logical >> 2) * 32;
    const int c0 = (logical & 3) * 64;

    const int frow = lane & 15;
    const int fkg  = (lane >> 4) * 8;

    const ushort* ap = &xpad[(size_t)(m0 + wv*16 + frow)*544 + fkg];
    const ushort* bp0 = &Bt[(size_t)(c0 +      frow)*544 + fkg];
    const ushort* bp1 = &Bt[(size_t)(c0 + 16 + frow)*544 + fkg];
    const ushort* bp2 = &Bt[(size_t)(c0 + 32 + frow)*544 + fkg];
    const ushort* bp3 = &Bt[(size_t)(c0 + 48 + frow)*544 + fkg];

    f32x4 acc[4];
    #pragma unroll
    for (int j = 0; j < 4; ++j) acc[j] = (f32x4)0.f;

    #pragma unroll 2
    for (int k0 = 0; k0 < 544; k0 += 32) {
        short8 af = *reinterpret_cast<const short8*>(ap + k0);
        short8 b0 = *reinterpret_cast<const short8*>(bp0 + k0);
        short8 b1 = *reinterpret_cast<const short8*>(bp1 + k0);
        short8 b2 = *reinterpret_cast<const short8*>(bp2 + k0);
        short8 b3 = *reinterpret_cast<const short8*>(bp3 + k0);
        acc[0] = __builtin_amdgcn_mfma_f32_16x16x32_bf16(af, b0, acc[0], 0, 0, 0);
        acc[1] = __builtin_amdgcn_mfma_f32_16x16x32_bf16(af, b1, acc[1], 0, 0, 0);
        acc[2] = __builtin_amdgcn_mfma_f32_16x16x32_bf16(af, b2, acc[2], 0, 0, 0);
        acc[3] = __builtin_amdgcn_mfma_f32_16x16x32_bf16(af, b3, acc[3], 0, 0, 0);
    }

    // ---- epilogue: transpose through LDS; emit bf16 rows + fused al/ar ----
    {
        const int rb = wv*16 + (lane >> 4)*4;
        const int cb = lane & 15;
        #pragma unroll
        for (int j = 0; j < 4; ++j)
            #pragma unroll
            for (int r2 = 0; r2 < 4; ++r2)
                ep[(rb + r2)*68 + j*16 + cb] = acc[j][r2];
    }
    __syncthreads();
    {
        const int rl = t >> 2;
        const int cq = (t & 3) * 16;
        const int row = m0 + rl;
        if (row < N) {
            const float* s = &ep[rl*68 + cq];
            float vals[16];
            #pragma unroll
            for (int i = 0; i < 16; ++i) vals[i] = s[i];
            uint u[8];
            #pragma unroll
            for (int i = 0; i < 8; ++i)
                u[i] = (uint)f2bf(vals[2*i]) | ((uint)f2bf(vals[2*i+1]) << 16);
            ushort* db = &xhb[(size_t)row*256 + c0 + cq];
            *reinterpret_cast<uint4*>(db)     = make_uint4(u[0], u[1], u[2], u[3]);
            *reinterpret_cast<uint4*>(db + 8) = make_uint4(u[4], u[5], u[6], u[7]);
            float pl = 0.f, pr = 0.f;
            #pragma unroll
            for (int i = 0; i < 16; ++i) {
                pl = fmaf(vals[i], att_l[c0 + cq + i], pl);
                pr = fmaf(vals[i], att_r[c0 + cq + i], pr);
            }
            pl += __shfl_xor(pl, 1, 64);
            pr += __shfl_xor(pr, 1, 64);
            if ((t & 1) == 0) {
                const int head = (c0 >> 5) + ((t & 3) >> 1);
                al[(size_t)row*8 + head] = pl;
                ar[(size_t)row*8 + head] = pr;
            }
        }
    }
}

// ---------------- per-dst single-pass softmax aggregation (no max-shift; unroll x4) ----------------
__global__ __launch_bounds__(256) void k_agg(
    const ushort* __restrict__ xhb,
    const float* __restrict__ al, const float* __restrict__ ar,
    const float* __restrict__ onehot, const uint* __restrict__ ohb,
    const float* __restrict__ bias,
    const int* __restrict__ row_start, const int* __restrict__ csr,
    float* __restrict__ out_x, float* __restrict__ out_oh, int N) {
    const int wave = threadIdx.x >> 6;
    const int lane = threadIdx.x & 63;
    const int n = blockIdx.x * 4 + wave;
    if (n >= N) return;
    const int h = lane >> 3;
    const float ard = ar[(size_t)n*8 + h];

    float a_self = al[(size_t)n*8 + h] + ard;
    a_self = fmaxf(a_self, NEG_SLOPE * a_self);
    float e_self = __expf(a_self);
    uint2 xsb = *reinterpret_cast<const uint2*>(&xhb[(size_t)n*256 + lane*4]);
    float4 acc;
    acc.x = e_self * bflo(xsb.x); acc.y = e_self * bfhi(xsb.x);
    acc.z = e_self * bflo(xsb.y); acc.w = e_self * bfhi(xsb.y);
    float den = e_self;
    float oh0 = 0.f, oh1 = 0.f;

    const int beg = row_start[n], end = row_start[n+1];
    int i = beg;
    for (; i + 3 < end; i += 4) {
        const int s0 = csr[i], s1 = csr[i+1], s2 = csr[i+2], s3 = csr[i+3];
        const float al0 = al[(size_t)s0*8 + h], al1 = al[(size_t)s1*8 + h];
        const float al2 = al[(size_t)s2*8 + h], al3 = al[(size_t)s3*8 + h];
        const uint2 xb0 = *reinterpret_cast<const uint2*>(&xhb[(size_t)s0*256 + lane*4]);
        const uint2 xb1 = *reinterpret_cast<const uint2*>(&xhb[(size_t)s1*256 + lane*4]);
        const uint2 xb2 = *reinterpret_cast<const uint2*>(&xhb[(size_t)s2*256 + lane*4]);
        const uint2 xb3 = *reinterpret_cast<const uint2*>(&xhb[(size_t)s3*256 + lane*4]);
        const uint ob0 = ohb[(size_t)s0*64 + lane];
        const uint ob1 = ohb[(size_t)s1*64 + lane];
        const uint ob2 = ohb[(size_t)s2*64 + lane];
        const uint ob3 = ohb[(size_t)s3*64 + lane];
        float a0 = al0 + ard; a0 = fmaxf(a0, NEG_SLOPE * a0);
        float a1 = al1 + ard; a1 = fmaxf(a1, NEG_SLOPE * a1);
        float a2 = al2 + ard; a2 = fmaxf(a2, NEG_SLOPE * a2);
        float a3 = al3 + ard; a3 = fmaxf(a3, NEG_SLOPE * a3);
        const float e0 = __expf(a0), e1 = __expf(a1), e2 = __expf(a2), e3 = __expf(a3);
        acc.x = fmaf(e0, bflo(xb0.x), fmaf(e1, bflo(xb1.x), fmaf(e2, bflo(xb2.x), fmaf(e3, bflo(xb3.x), acc.x))));
        acc.y = fmaf(e0, bfhi(xb0.x), fmaf(e1, bfhi(xb1.x), fmaf(e2, bfhi(xb2.x), fmaf(e3, bfhi(xb3.x), acc.y))));
        acc.z = fmaf(e0, bflo(xb0.y), fmaf(e1, bflo(xb1.y), fmaf(e2, bflo(xb2.y), fmaf(e3, bflo(xb3.y), acc.z))));
        acc.w = fmaf(e0, bfhi(xb0.y), fmaf(e1, bfhi(xb1.y), fmaf(e2, bfhi(xb2.y), fmaf(e3, bfhi(xb3.y), acc.w))));
        den += (e0 + e1) + (e2 + e3);
        oh0 += (bflo(ob0) + bflo(ob1)) + (bflo(ob2) + bflo(ob3));
        oh1 += (bfhi(ob0) + bfhi(ob1)) + (bfhi(ob2) + bfhi(ob3));
    }
    for (; i < end; ++i) {
        const int s0 = csr[i];
        float a0 = al[(size_t)s0*8 + h] + ard;
        a0 = fmaxf(a0, NEG_SLOPE * a0);
        const float e0 = __expf(a0);
        const uint2 xb0 = *reinterpret_cast<const uint2*>(&xhb[(size_t)s0*256 + lane*4]);
        const uint ob0 = ohb[(size_t)s0*64 + lane];
        acc.x = fmaf(e0, bflo(xb0.x), acc.x);
        acc.y = fmaf(e0, bfhi(xb0.x), acc.y);
        acc.z = fmaf(e0, bflo(xb0.y), acc.z);
        acc.w = fmaf(e0, bfhi(xb0.y), acc.w);
        den += e0;
        oh0 += bflo(ob0);
        oh1 += bfhi(ob0);
    }
    const float inv = 1.f / den;
    const float4 bv = *reinterpret_cast<const float4*>(&bias[lane*4]);
    float4 o;
    o.x = fmaf(acc.x, inv, bv.x);
    o.y = fmaf(acc.y, inv, bv.y);
    o.z = fmaf(acc.z, inv, bv.z);
    o.w = fmaf(acc.w, inv, bv.w);
    *reinterpret_cast<float4*>(&out_x[(size_t)n*256 + lane*4]) = o;
    float2 so = *reinterpret_cast<const float2*>(&onehot[(size_t)n*128 + lane*2]);  // self f32
    float2 oo;
    oo.x = oh0 + 2.f*so.x;
    oo.y = oh1 + 2.f*so.y;
    *reinterpret_cast<float2*>(&out_oh[(size_t)n*128 + lane*2]) = oo;
}

// ---------------- launcher ----------------
extern "C" void kernel_launch(void* const* d_in, const int* in_sizes, int n_in,
                              void* d_out, int out_size, void* d_ws, size_t ws_size,
                              hipStream_t stream) {
    const float* x      = (const float*)d_in[0];
    const float* onehot = (const float*)d_in[1];
    const int*   adj    = (const int*)d_in[2];
    const float* lin_w  = (const float*)d_in[4];
    const float* att_l  = (const float*)d_in[5];
    const float* att_r  = (const float*)d_in[6];
    const float* bias   = (const float*)d_in[7];
    const float* c1w    = (const float*)d_in[8];
    const float* c1b    = (const float*)d_in[9];
    const float* c2w    = (const float*)d_in[10];
    const float* c2b    = (const float*)d_in[11];
    const float* l2w    = (const float*)d_in[12];
    const float* l2b    = (const float*)d_in[13];

    const int N = in_sizes[0] / 512;
    const int E = in_sizes[2] / 2;
    const int* src = adj;
    const int* dst = adj + E;

    float* out_x  = (float*)d_out;
    float* out_oh = out_x + (size_t)N * 256;

    // workspace layout
    ushort* xpad     = (ushort*)d_ws;                       // N*544 bf16
    ushort* Bt       = xpad + (size_t)N * 544;              // 256*544 bf16
    ushort* xhb      = Bt + (size_t)256 * 544;              // N*256 bf16
    uint*   ohb      = (uint*)(xhb + (size_t)N * 256);      // N*64 packed bf16x2
    float*  al       = (float*)(ohb + (size_t)N * 64);      // N*8
    float*  ar       = al + (size_t)N * 8;                  // N*8
    int*   row_start = (int*)(ar + (size_t)N * 8);          // N+1
    int*   cursor    = row_start + (N + 1);                 // N
    int*   csr       = cursor + N;                          // E

    const int EB = (E + 255) / 256;
    const int GB = ((N + 31) / 32) * 4;

    k_conv_wave<<<(N + 3) / 4, 256, 0, stream>>>(x, onehot, c1w, c1b, c2w, c2b, l2w, l2b, xpad, ohb, cursor, N);
    k_prep<<<EB, 256, 0, stream>>>(lin_w, Bt, dst, cursor, E);
    k_scan<<<1, 1024, 0, stream>>>(cursor, row_start, N);
    k_gemm_mfma<<<GB, 128, 0, stream>>>(xpad, Bt, att_l, att_r, xhb, al, ar,
                                        src, dst, row_start, cursor, csr, N, E);
    k_agg<<<(N + 3) / 4, 256, 0, stream>>>(xhb, al, ar, onehot, ohb, bias, row_start, csr, out_x, out_oh, N);
}

// Round 12
// 171.727 us; speedup vs baseline: 1.1407x; 1.0331x over previous
//
#include <hip/hip_runtime.h>

#define NEG_SLOPE 0.2f

typedef __attribute__((ext_vector_type(4))) float f32x4;
typedef __attribute__((ext_vector_type(2))) float f32x2;
typedef __attribute__((ext_vector_type(8))) short short8;

__device__ __forceinline__ f32x2 mk2(float a, float b) { f32x2 r; r[0] = a; r[1] = b; return r; }

__device__ __forceinline__ f32x2 FMA2(f32x2 a, f32x2 b, f32x2 c) {
#if __has_builtin(__builtin_elementwise_fma)
    return __builtin_elementwise_fma(a, b, c);
#else
    f32x2 r; r[0] = fmaf(a[0], b[0], c[0]); r[1] = fmaf(a[1], b[1], c[1]); return r;
#endif
}

__device__ __forceinline__ ushort f2bf(float f) {
    uint u = __float_as_uint(f);
    u += 0x7FFFu + ((u >> 16) & 1u);
    return (ushort)(u >> 16);
}
__device__ __forceinline__ float bflo(uint u) { return __uint_as_float(u << 16); }
__device__ __forceinline__ float bfhi(uint u) { return __uint_as_float(u & 0xffff0000u); }

// ---------------- conv pipe (conv2 via MFMA) + x->bf16 prep + cursor zero, wave-per-node ----------------
__global__ __launch_bounds__(256) void k_conv_wave(
    const float* __restrict__ x, const float* __restrict__ onehot,
    const float* __restrict__ c1w, const float* __restrict__ c1b,
    const float* __restrict__ c2w, const float* __restrict__ c2b,
    const float* __restrict__ l2w, const float* __restrict__ l2b,
    ushort* __restrict__ xpad, uint* __restrict__ ohb, int* __restrict__ cursor, int N) {
    __shared__ ushort Hall[4][1056];

    // fused: zero cursor (completes before k_prep's atomics via stream order)
    const int gid = blockIdx.x * 256 + threadIdx.x;
    if (gid < N) cursor[gid] = 0;

    const int wave = threadIdx.x >> 6;
    const int lane = threadIdx.x & 63;
    const int n = blockIdx.x * 4 + wave;
    if (n >= N) return;
    ushort* H = Hall[wave];

    // fused prepX: x row f32 -> xpad bf16 cols 0..511 (+ zero pad 520..543)
    {
        const float* xp = &x[(size_t)n*512 + lane*8];
        float4 lo = *reinterpret_cast<const float4*>(xp);
        float4 hi = *reinterpret_cast<const float4*>(xp + 4);
        uint4 w;
        w.x = (uint)f2bf(lo.x) | ((uint)f2bf(lo.y) << 16);
        w.y = (uint)f2bf(lo.z) | ((uint)f2bf(lo.w) << 16);
        w.z = (uint)f2bf(hi.x) | ((uint)f2bf(hi.y) << 16);
        w.w = (uint)f2bf(hi.z) | ((uint)f2bf(hi.w) << 16);
        *reinterpret_cast<uint4*>(&xpad[(size_t)n*544 + lane*8]) = w;
        if (lane < 3) {
            const uint4 z = make_uint4(0,0,0,0);
            *reinterpret_cast<uint4*>(&xpad[(size_t)n*544 + 520 + lane*8]) = z;
        }
    }

    float2 in2 = *reinterpret_cast<const float2*>(&onehot[(size_t)n * 128 + lane * 2]);
    ohb[(size_t)n*64 + lane] = (uint)f2bf(in2.x) | ((uint)f2bf(in2.y) << 16);
    float v0 = log1pf(in2.x);
    float v1 = log1pf(in2.y);

    // bitonic sort of 128 elements, i = 2*lane + r; fully in registers
    #pragma unroll
    for (int k = 2; k <= 128; k <<= 1) {
        const bool asc = ((lane & (k >> 1)) == 0);
        #pragma unroll
        for (int j = k >> 1; j >= 2; j >>= 1) {
            const int m = j >> 1;
            float p0 = __shfl_xor(v0, m, 64);
            float p1 = __shfl_xor(v1, m, 64);
            const bool keepmin = (((lane & m) == 0) == asc);
            v0 = keepmin ? fminf(v0, p0) : fmaxf(v0, p0);
            v1 = keepmin ? fminf(v1, p1) : fmaxf(v1, p1);
        }
        float lo = fminf(v0, v1), hi = fmaxf(v0, v1);
        v0 = asc ? lo : hi;
        v1 = asc ? hi : lo;
    }

    float pm = __shfl_up(v1, 1, 64); if (lane == 0)  pm = 0.f;
    float pp = __shfl_down(v0, 1, 64); if (lane == 63) pp = 0.f;

    // conv1: 1->8, packed over the lane's two positions (f32)
    float h0[8], h1[8];
    {
        const f32x2 xm = mk2(pm, v0), x0 = mk2(v0, v1), xp2 = mk2(v1, pp);
        #pragma unroll
        for (int c = 0; c < 8; ++c) {
            const float w0 = c1w[c*3+0], w1 = c1w[c*3+1], w2 = c1w[c*3+2], b = c1b[c];
            f32x2 h = FMA2(xm, mk2(w0, w0), FMA2(x0, mk2(w1, w1), FMA2(xp2, mk2(w2, w2), mk2(b, b))));
            h0[c] = fmaxf(h[0], 0.f);
            h1[c] = fmaxf(h[1], 0.f);
        }
    }

    // stage h (bf16) into LDS rows; zero boundary rows
    {
        if (lane == 0) {
            const uint4 z = make_uint4(0,0,0,0);
            *reinterpret_cast<uint4*>(&H[0*8])   = z;
            *reinterpret_cast<uint4*>(&H[130*8]) = z;
            *reinterpret_cast<uint4*>(&H[65*8])  = z;
        }
        uint4 w0, w1;
        w0.x = (uint)f2bf(h0[0]) | ((uint)f2bf(h0[1]) << 16);
        w0.y = (uint)f2bf(h0[2]) | ((uint)f2bf(h0[3]) << 16);
        w0.z = (uint)f2bf(h0[4]) | ((uint)f2bf(h0[5]) << 16);
        w0.w = (uint)f2bf(h0[6]) | ((uint)f2bf(h0[7]) << 16);
        w1.x = (uint)f2bf(h1[0]) | ((uint)f2bf(h1[1]) << 16);
        w1.y = (uint)f2bf(h1[2]) | ((uint)f2bf(h1[3]) << 16);
        w1.z = (uint)f2bf(h1[4]) | ((uint)f2bf(h1[5]) << 16);
        w1.w = (uint)f2bf(h1[6]) | ((uint)f2bf(h1[7]) << 16);
        *reinterpret_cast<uint4*>(&H[(66 + lane)*8]) = w0;   // pos 2l   -> row 2l+1 -> slot 66+l
        *reinterpret_cast<uint4*>(&H[(lane + 1)*8])  = w1;   // pos 2l+1 -> row 2l+2 -> slot l+1
    }

    // conv2 as MFMA: D[pos][co] = sum_k A[pos][k] * B[k][co], k = tap*8 + ci
    const int co = lane & 15;
    const int g2 = lane >> 4;
    short8 bfrag;
    #pragma unroll
    for (int j = 0; j < 8; ++j) bfrag[j] = 0;
    if (g2 < 3) {
        #pragma unroll
        for (int j = 0; j < 8; ++j) bfrag[j] = (short)f2bf(c2w[(co*8 + j)*3 + g2]);
    }
    const float bias_c = c2b[co];
    const f32x4 zacc = (f32x4)0.f;

    float poolv = 0.f;
    #pragma unroll
    for (int s = 0; s < 8; ++s) {
        const int q = s*16 + co + g2;
        const int slot = (q >> 1) + (q & 1)*66;
        short8 afrag = *reinterpret_cast<const short8*>(&H[slot*8]);
        f32x4 d = __builtin_amdgcn_mfma_f32_16x16x32_bf16(afrag, bfrag, zacc, 0, 0, 0);
        poolv += fmaxf(d[0] + bias_c, 0.f);
        poolv += fmaxf(d[1] + bias_c, 0.f);
        poolv += fmaxf(d[2] + bias_c, 0.f);
        poolv += fmaxf(d[3] + bias_c, 0.f);
    }
    poolv += __shfl_xor(poolv, 16, 64);
    poolv += __shfl_xor(poolv, 32, 64);

    // linear 16 -> 8 (gather pooled[c] from lane c)
    float r = (lane < 8) ? l2b[lane] : 0.f;
    #pragma unroll
    for (int c = 0; c < 16; ++c) {
        float pc = __shfl(poolv, c, 64);
        if (lane < 8) r = fmaf(pc * (1.f/128.f), l2w[c*8 + lane], r);
    }
    if (lane < 8) xpad[(size_t)n*544 + 512 + lane] = f2bf(r);
}

// ---------------- fused: lin_w -> Bt (blocks 0..255) + degree count (all blocks) ----------------
__global__ __launch_bounds__(256) void k_prep(
    const float* __restrict__ lin_w, ushort* __restrict__ Bt,
    const int* __restrict__ dst, int* __restrict__ cursor, int E) {
    const int gid = blockIdx.x * 256 + threadIdx.x;
    if (gid < E) atomicAdd(&cursor[dst[gid]], 1);
    const int col = blockIdx.x;
    if (col < 256) {
        for (int k = threadIdx.x; k < 544; k += 256) {
            float v = (k < 520) ? lin_w[(size_t)k*256 + col] : 0.f;
            Bt[(size_t)col*544 + k] = f2bf(v);
        }
    }
}

// ---------------- single-pass block scan: 20 elems/thread, 2 barriers; zeroes deg ----------------
__global__ __launch_bounds__(1024) void k_scan(int* __restrict__ deg, int* __restrict__ row_start, int N) {
    __shared__ int wsum[16];
    const int t = threadIdx.x;
    const int w = t >> 6, ln = t & 63;
    const int base = t * 20;
    int v[20];
    int run = 0;
    #pragma unroll
    for (int i = 0; i < 20; ++i) {
        const int idx = base + i;
        int d = 0;
        if (idx < N) { d = deg[idx]; deg[idx] = 0; }
        run += d;
        v[i] = run;
    }
    int s = run;
    #pragma unroll
    for (int d = 1; d < 64; d <<= 1) {
        int u = __shfl_up(s, d, 64);
        if (ln >= d) s += u;
    }
    if (ln == 63) wsum[w] = s;
    __syncthreads();
    if (w == 0) {
        int ws = (ln < 16) ? wsum[ln] : 0;
        int e2 = ws;
        #pragma unroll
        for (int d = 1; d < 16; d <<= 1) {
            int u = __shfl_up(e2, d, 64);
            if (ln >= d) e2 += u;
        }
        if (ln < 16) wsum[ln] = e2 - ws;
    }
    __syncthreads();
    const int off = (s - run) + wsum[w];
    if (t == 0) row_start[0] = 0;
    #pragma unroll
    for (int i = 0; i < 20; ++i) {
        const int idx = base + i;
        if (idx < N) row_start[idx + 1] = off + v[i];
    }
}

// ---------------- bf16-MFMA GEMM (2-deep reg pipeline) + CSR fill AFTER the K-loop ----------------
__global__ __launch_bounds__(128) void k_gemm_mfma(
    const ushort* __restrict__ xpad, const ushort* __restrict__ Bt,
    const float* __restrict__ att_l, const float* __restrict__ att_r,
    ushort* __restrict__ xhb, float* __restrict__ al, float* __restrict__ ar,
    const int* __restrict__ src, const int* __restrict__ dst,
    const int* __restrict__ row_start, int* __restrict__ cursor, int* __restrict__ csr,
    int N, int E) {
    __shared__ __align__(16) float ep[32*68];

    const int t = threadIdx.x;
    const int wv = t >> 6, lane = t & 63;

    // bijective XCD swizzle (m204)
    const int nwg = gridDim.x;
    const int q = nwg >> 3, r = nwg & 7;
    const int xcd = blockIdx.x & 7, idx = blockIdx.x >> 3;
    const int logical = (xcd < r ? xcd*(q+1) : r*(q+1) + (xcd-r)*q) + idx;
    const int m0 = (logical >> 2) * 32;
    const int c0 = (logical & 3) * 64;

    const int frow = lane & 15;
    const int fkg  = (lane >> 4) * 8;

    const ushort* ap = &xpad[(size_t)(m0 + wv*16 + frow)*544 + fkg];
    const ushort* bp0 = &Bt[(size_t)(c0 +      frow)*544 + fkg];
    const ushort* bp1 = &Bt[(size_t)(c0 + 16 + frow)*544 + fkg];
    const ushort* bp2 = &Bt[(size_t)(c0 + 32 + frow)*544 + fkg];
    const ushort* bp3 = &Bt[(size_t)(c0 + 48 + frow)*544 + fkg];

    f32x4 acc[4];
    #pragma unroll
    for (int j = 0; j < 4; ++j) acc[j] = (f32x4)0.f;

    // 2-deep register pipeline over the 17 K-steps (fully unrolled, static indices)
    short8 afr[2], br0[2], br1[2], br2[2], br3[2];
#define LOADSET(B_, K_)                                                  \
    {                                                                    \
        afr[B_] = *reinterpret_cast<const short8*>(ap  + (K_));          \
        br0[B_] = *reinterpret_cast<const short8*>(bp0 + (K_));          \
        br1[B_] = *reinterpret_cast<const short8*>(bp1 + (K_));          \
        br2[B_] = *reinterpret_cast<const short8*>(bp2 + (K_));          \
        br3[B_] = *reinterpret_cast<const short8*>(bp3 + (K_));          \
    }
    LOADSET(0, 0)
    #pragma unroll
    for (int s = 0; s < 17; ++s) {
        const int b = s & 1;
        if (s + 1 < 17) LOADSET((s + 1) & 1, (s + 1) * 32)
        acc[0] = __builtin_amdgcn_mfma_f32_16x16x32_bf16(afr[b], br0[b], acc[0], 0, 0, 0);
        acc[1] = __builtin_amdgcn_mfma_f32_16x16x32_bf16(afr[b], br1[b], acc[1], 0, 0, 0);
        acc[2] = __builtin_amdgcn_mfma_f32_16x16x32_bf16(afr[b], br2[b], acc[2], 0, 0, 0);
        acc[3] = __builtin_amdgcn_mfma_f32_16x16x32_bf16(afr[b], br3[b], acc[3], 0, 0, 0);
    }
#undef LOADSET

    // fused CSR fill — AFTER the K-loop so the atomic's latency overlaps the epilogue,
    // not the head of the vmcnt queue (R11 lesson: vmcnt waits are oldest-first).
    {
        const int e = blockIdx.x * 128 + t;
        if (e < E) {
            const int d = dst[e];
            const int p = atomicAdd(&cursor[d], 1);
            csr[row_start[d] + p] = src[e];
        }
    }

    // ---- epilogue: transpose through LDS; emit bf16 rows + fused al/ar ----
    {
        const int rb = wv*16 + (lane >> 4)*4;
        const int cb = lane & 15;
        #pragma unroll
        for (int j = 0; j < 4; ++j)
            #pragma unroll
            for (int r2 = 0; r2 < 4; ++r2)
                ep[(rb + r2)*68 + j*16 + cb] = acc[j][r2];
    }
    __syncthreads();
    {
        const int rl = t >> 2;
        const int cq = (t & 3) * 16;
        const int row = m0 + rl;
        if (row < N) {
            const float* s = &ep[rl*68 + cq];
            float vals[16];
            #pragma unroll
            for (int i = 0; i < 16; ++i) vals[i] = s[i];
            uint u[8];
            #pragma unroll
            for (int i = 0; i < 8; ++i)
                u[i] = (uint)f2bf(vals[2*i]) | ((uint)f2bf(vals[2*i+1]) << 16);
            ushort* db = &xhb[(size_t)row*256 + c0 + cq];
            *reinterpret_cast<uint4*>(db)     = make_uint4(u[0], u[1], u[2], u[3]);
            *reinterpret_cast<uint4*>(db + 8) = make_uint4(u[4], u[5], u[6], u[7]);
            float pl = 0.f, pr = 0.f;
            #pragma unroll
            for (int i = 0; i < 16; ++i) {
                pl = fmaf(vals[i], att_l[c0 + cq + i], pl);
                pr = fmaf(vals[i], att_r[c0 + cq + i], pr);
            }
            pl += __shfl_xor(pl, 1, 64);
            pr += __shfl_xor(pr, 1, 64);
            if ((t & 1) == 0) {
                const int head = (c0 >> 5) + ((t & 3) >> 1);
                al[(size_t)row*8 + head] = pl;
                ar[(size_t)row*8 + head] = pr;
            }
        }
    }
}

// ---------------- per-dst single-pass softmax aggregation (no max-shift; unroll x4) ----------------
__global__ __launch_bounds__(256) void k_agg(
    const ushort* __restrict__ xhb,
    const float* __restrict__ al, const float* __restrict__ ar,
    const float* __restrict__ onehot, const uint* __restrict__ ohb,
    const float* __restrict__ bias,
    const int* __restrict__ row_start, const int* __restrict__ csr,
    float* __restrict__ out_x, float* __restrict__ out_oh, int N) {
    const int wave = threadIdx.x >> 6;
    const int lane = threadIdx.x & 63;
    const int n = blockIdx.x * 4 + wave;
    if (n >= N) return;
    const int h = lane >> 3;
    const float ard = ar[(size_t)n*8 + h];

    float a_self = al[(size_t)n*8 + h] + ard;
    a_self = fmaxf(a_self, NEG_SLOPE * a_self);
    float e_self = __expf(a_self);
    uint2 xsb = *reinterpret_cast<const uint2*>(&xhb[(size_t)n*256 + lane*4]);
    float4 acc;
    acc.x = e_self * bflo(xsb.x); acc.y = e_self * bfhi(xsb.x);
    acc.z = e_self * bflo(xsb.y); acc.w = e_self * bfhi(xsb.y);
    float den = e_self;
    float oh0 = 0.f, oh1 = 0.f;

    const int beg = row_start[n], end = row_start[n+1];
    int i = beg;
    for (; i + 3 < end; i += 4) {
        const int s0 = csr[i], s1 = csr[i+1], s2 = csr[i+2], s3 = csr[i+3];
        const float al0 = al[(size_t)s0*8 + h], al1 = al[(size_t)s1*8 + h];
        const float al2 = al[(size_t)s2*8 + h], al3 = al[(size_t)s3*8 + h];
        const uint2 xb0 = *reinterpret_cast<const uint2*>(&xhb[(size_t)s0*256 + lane*4]);
        const uint2 xb1 = *reinterpret_cast<const uint2*>(&xhb[(size_t)s1*256 + lane*4]);
        const uint2 xb2 = *reinterpret_cast<const uint2*>(&xhb[(size_t)s2*256 + lane*4]);
        const uint2 xb3 = *reinterpret_cast<const uint2*>(&xhb[(size_t)s3*256 + lane*4]);
        const uint ob0 = ohb[(size_t)s0*64 + lane];
        const uint ob1 = ohb[(size_t)s1*64 + lane];
        const uint ob2 = ohb[(size_t)s2*64 + lane];
        const uint ob3 = ohb[(size_t)s3*64 + lane];
        float a0 = al0 + ard; a0 = fmaxf(a0, NEG_SLOPE * a0);
        float a1 = al1 + ard; a1 = fmaxf(a1, NEG_SLOPE * a1);
        float a2 = al2 + ard; a2 = fmaxf(a2, NEG_SLOPE * a2);
        float a3 = al3 + ard; a3 = fmaxf(a3, NEG_SLOPE * a3);
        const float e0 = __expf(a0), e1 = __expf(a1), e2 = __expf(a2), e3 = __expf(a3);
        acc.x = fmaf(e0, bflo(xb0.x), fmaf(e1, bflo(xb1.x), fmaf(e2, bflo(xb2.x), fmaf(e3, bflo(xb3.x), acc.x))));
        acc.y = fmaf(e0, bfhi(xb0.x), fmaf(e1, bfhi(xb1.x), fmaf(e2, bfhi(xb2.x), fmaf(e3, bfhi(xb3.x), acc.y))));
        acc.z = fmaf(e0, bflo(xb0.y), fmaf(e1, bflo(xb1.y), fmaf(e2, bflo(xb2.y), fmaf(e3, bflo(xb3.y), acc.z))));
        acc.w = fmaf(e0, bfhi(xb0.y), fmaf(e1, bfhi(xb1.y), fmaf(e2, bfhi(xb2.y), fmaf(e3, bfhi(xb3.y), acc.w))));
        den += (e0 + e1) + (e2 + e3);
        oh0 += (bflo(ob0) + bflo(ob1)) + (bflo(ob2) + bflo(ob3));
        oh1 += (bfhi(ob0) + bfhi(ob1)) + (bfhi(ob2) + bfhi(ob3));
    }
    for (; i < end; ++i) {
        const int s0 = csr[i];
        float a0 = al[(size_t)s0*8 + h] + ard;
        a0 = fmaxf(a0, NEG_SLOPE * a0);
        const float e0 = __expf(a0);
        const uint2 xb0 = *reinterpret_cast<const uint2*>(&xhb[(size_t)s0*256 + lane*4]);
        const uint ob0 = ohb[(size_t)s0*64 + lane];
        acc.x = fmaf(e0, bflo(xb0.x), acc.x);
        acc.y = fmaf(e0, bfhi(xb0.x), acc.y);
        acc.z = fmaf(e0, bflo(xb0.y), acc.z);
        acc.w = fmaf(e0, bfhi(xb0.y), acc.w);
        den += e0;
        oh0 += bflo(ob0);
        oh1 += bfhi(ob0);
    }
    const float inv = 1.f / den;
    const float4 bv = *reinterpret_cast<const float4*>(&bias[lane*4]);
    float4 o;
    o.x = fmaf(acc.x, inv, bv.x);
    o.y = fmaf(acc.y, inv, bv.y);
    o.z = fmaf(acc.z, inv, bv.z);
    o.w = fmaf(acc.w, inv, bv.w);
    *reinterpret_cast<float4*>(&out_x[(size_t)n*256 + lane*4]) = o;
    float2 so = *reinterpret_cast<const float2*>(&onehot[(size_t)n*128 + lane*2]);  // self f32
    float2 oo;
    oo.x = oh0 + 2.f*so.x;
    oo.y = oh1 + 2.f*so.y;
    *reinterpret_cast<float2*>(&out_oh[(size_t)n*128 + lane*2]) = oo;
}

// ---------------- launcher ----------------
extern "C" void kernel_launch(void* const* d_in, const int* in_sizes, int n_in,
                              void* d_out, int out_size, void* d_ws, size_t ws_size,
                              hipStream_t stream) {
    const float* x      = (const float*)d_in[0];
    const float* onehot = (const float*)d_in[1];
    const int*   adj    = (const int*)d_in[2];
    const float* lin_w  = (const float*)d_in[4];
    const float* att_l  = (const float*)d_in[5];
    const float* att_r  = (const float*)d_in[6];
    const float* bias   = (const float*)d_in[7];
    const float* c1w    = (const float*)d_in[8];
    const float* c1b    = (const float*)d_in[9];
    const float* c2w    = (const float*)d_in[10];
    const float* c2b    = (const float*)d_in[11];
    const float* l2w    = (const float*)d_in[12];
    const float* l2b    = (const float*)d_in[13];

    const int N = in_sizes[0] / 512;
    const int E = in_sizes[2] / 2;
    const int* src = adj;
    const int* dst = adj + E;

    float* out_x  = (float*)d_out;
    float* out_oh = out_x + (size_t)N * 256;

    // workspace layout
    ushort* xpad     = (ushort*)d_ws;                       // N*544 bf16
    ushort* Bt       = xpad + (size_t)N * 544;              // 256*544 bf16
    ushort* xhb      = Bt + (size_t)256 * 544;              // N*256 bf16
    uint*   ohb      = (uint*)(xhb + (size_t)N * 256);      // N*64 packed bf16x2
    float*  al       = (float*)(ohb + (size_t)N * 64);      // N*8
    float*  ar       = al + (size_t)N * 8;                  // N*8
    int*   row_start = (int*)(ar + (size_t)N * 8);          // N+1
    int*   cursor    = row_start + (N + 1);                 // N
    int*   csr       = cursor + N;                          // E

    const int EB = (E + 255) / 256;
    const int GB = ((N + 31) / 32) * 4;

    k_conv_wave<<<(N + 3) / 4, 256, 0, stream>>>(x, onehot, c1w, c1b, c2w, c2b, l2w, l2b, xpad, ohb, cursor, N);
    k_prep<<<EB, 256, 0, stream>>>(lin_w, Bt, dst, cursor, E);
    k_scan<<<1, 1024, 0, stream>>>(cursor, row_start, N);
    k_gemm_mfma<<<GB, 128, 0, stream>>>(xpad, Bt, att_l, att_r, xhb, al, ar,
                                        src, dst, row_start, cursor, csr, N, E);
    k_agg<<<(N + 3) / 4, 256, 0, stream>>>(xhb, al, ar, onehot, ohb, bias, row_start, csr, out_x, out_oh, N);
}

// Round 13
// 164.119 us; speedup vs baseline: 1.1936x; 1.0464x over previous
//
#include <hip/hip_runtime.h>

#define NEG_SLOPE 0.2f

typedef __attribute__((ext_vector_type(4))) float f32x4;
typedef __attribute__((ext_vector_type(2))) float f32x2;
typedef __attribute__((ext_vector_type(8))) short short8;

__device__ __forceinline__ f32x2 mk2(float a, float b) { f32x2 r; r[0] = a; r[1] = b; return r; }

__device__ __forceinline__ f32x2 FMA2(f32x2 a, f32x2 b, f32x2 c) {
#if __has_builtin(__builtin_elementwise_fma)
    return __builtin_elementwise_fma(a, b, c);
#else
    f32x2 r; r[0] = fmaf(a[0], b[0], c[0]); r[1] = fmaf(a[1], b[1], c[1]); return r;
#endif
}

__device__ __forceinline__ ushort f2bf(float f) {
    uint u = __float_as_uint(f);
    u += 0x7FFFu + ((u >> 16) & 1u);
    return (ushort)(u >> 16);
}
__device__ __forceinline__ float bflo(uint u) { return __uint_as_float(u << 16); }
__device__ __forceinline__ float bfhi(uint u) { return __uint_as_float(u & 0xffff0000u); }

// xpadA fragment-tiled layout: element (n,k) ->
//   nt=n>>6, g16=(n>>4)&3, r16=n&15, s=k>>5, kc=(k>>3)&3, j=k&7
//   ushort addr = ((nt*17+s)*4 + g16)*512 + (kc*16+r16)*8 + j
// BtT: (col,k) -> s=k>>5, cs=col>>4, fcol=col&15
//   ushort addr = (s*16+cs)*512 + (kc*16+fcol)*8 + j

// ---------------- conv pipe (conv2 via MFMA) + x->bf16 frag-tiled prep + cursor zero ----------------
__global__ __launch_bounds__(256) void k_conv_wave(
    const float* __restrict__ x, const float* __restrict__ onehot,
    const float* __restrict__ c1w, const float* __restrict__ c1b,
    const float* __restrict__ c2w, const float* __restrict__ c2b,
    const float* __restrict__ l2w, const float* __restrict__ l2b,
    ushort* __restrict__ xpadA, uint* __restrict__ ohb, int* __restrict__ cursor, int N) {
    __shared__ ushort Hall[4][1056];

    const int gid = blockIdx.x * 256 + threadIdx.x;
    if (gid < N) cursor[gid] = 0;

    const int wave = threadIdx.x >> 6;
    const int lane = threadIdx.x & 63;
    const int n = blockIdx.x * 4 + wave;
    if (n >= N) return;
    ushort* H = Hall[wave];

    const int nt = n >> 6, g16 = (n >> 4) & 3, r16 = n & 15;
    const size_t qstep = ((size_t)nt*17)*4 + g16;   // step-quarter index base (advance by 4 per step)

    // fused prepX: lane l holds k = l*8..l*8+7  ->  s=l>>2, kc=l&3
    {
        const float* xp = &x[(size_t)n*512 + lane*8];
        float4 lo = *reinterpret_cast<const float4*>(xp);
        float4 hi = *reinterpret_cast<const float4*>(xp + 4);
        uint4 w;
        w.x = (uint)f2bf(lo.x) | ((uint)f2bf(lo.y) << 16);
        w.y = (uint)f2bf(lo.z) | ((uint)f2bf(lo.w) << 16);
        w.z = (uint)f2bf(hi.x) | ((uint)f2bf(hi.y) << 16);
        w.w = (uint)f2bf(hi.z) | ((uint)f2bf(hi.w) << 16);
        const size_t a = (qstep + (size_t)(lane >> 2)*4)*512 + ((lane & 3)*16 + r16)*8;
        *reinterpret_cast<uint4*>(&xpadA[a]) = w;
    }

    float2 in2 = *reinterpret_cast<const float2*>(&onehot[(size_t)n * 128 + lane * 2]);
    ohb[(size_t)n*64 + lane] = (uint)f2bf(in2.x) | ((uint)f2bf(in2.y) << 16);
    float v0 = log1pf(in2.x);
    float v1 = log1pf(in2.y);

    // bitonic sort of 128 elements, fully in registers
    #pragma unroll
    for (int k = 2; k <= 128; k <<= 1) {
        const bool asc = ((lane & (k >> 1)) == 0);
        #pragma unroll
        for (int j = k >> 1; j >= 2; j >>= 1) {
            const int m = j >> 1;
            float p0 = __shfl_xor(v0, m, 64);
            float p1 = __shfl_xor(v1, m, 64);
            const bool keepmin = (((lane & m) == 0) == asc);
            v0 = keepmin ? fminf(v0, p0) : fmaxf(v0, p0);
            v1 = keepmin ? fminf(v1, p1) : fmaxf(v1, p1);
        }
        float lo = fminf(v0, v1), hi = fmaxf(v0, v1);
        v0 = asc ? lo : hi;
        v1 = asc ? hi : lo;
    }

    float pm = __shfl_up(v1, 1, 64); if (lane == 0)  pm = 0.f;
    float pp = __shfl_down(v0, 1, 64); if (lane == 63) pp = 0.f;

    float h0[8], h1[8];
    {
        const f32x2 xm = mk2(pm, v0), x0 = mk2(v0, v1), xp2 = mk2(v1, pp);
        #pragma unroll
        for (int c = 0; c < 8; ++c) {
            const float w0 = c1w[c*3+0], w1 = c1w[c*3+1], w2 = c1w[c*3+2], b = c1b[c];
            f32x2 h = FMA2(xm, mk2(w0, w0), FMA2(x0, mk2(w1, w1), FMA2(xp2, mk2(w2, w2), mk2(b, b))));
            h0[c] = fmaxf(h[0], 0.f);
            h1[c] = fmaxf(h[1], 0.f);
        }
    }

    // stage h (bf16) into LDS rows; zero boundary rows
    {
        if (lane == 0) {
            const uint4 z = make_uint4(0,0,0,0);
            *reinterpret_cast<uint4*>(&H[0*8])   = z;
            *reinterpret_cast<uint4*>(&H[130*8]) = z;
            *reinterpret_cast<uint4*>(&H[65*8])  = z;
        }
        uint4 w0, w1;
        w0.x = (uint)f2bf(h0[0]) | ((uint)f2bf(h0[1]) << 16);
        w0.y = (uint)f2bf(h0[2]) | ((uint)f2bf(h0[3]) << 16);
        w0.z = (uint)f2bf(h0[4]) | ((uint)f2bf(h0[5]) << 16);
        w0.w = (uint)f2bf(h0[6]) | ((uint)f2bf(h0[7]) << 16);
        w1.x = (uint)f2bf(h1[0]) | ((uint)f2bf(h1[1]) << 16);
        w1.y = (uint)f2bf(h1[2]) | ((uint)f2bf(h1[3]) << 16);
        w1.z = (uint)f2bf(h1[4]) | ((uint)f2bf(h1[5]) << 16);
        w1.w = (uint)f2bf(h1[6]) | ((uint)f2bf(h1[7]) << 16);
        *reinterpret_cast<uint4*>(&H[(66 + lane)*8]) = w0;
        *reinterpret_cast<uint4*>(&H[(lane + 1)*8])  = w1;
    }

    // conv2 as MFMA
    const int co = lane & 15;
    const int g2 = lane >> 4;
    short8 bfrag;
    #pragma unroll
    for (int j = 0; j < 8; ++j) bfrag[j] = 0;
    if (g2 < 3) {
        #pragma unroll
        for (int j = 0; j < 8; ++j) bfrag[j] = (short)f2bf(c2w[(co*8 + j)*3 + g2]);
    }
    const float bias_c = c2b[co];
    const f32x4 zacc = (f32x4)0.f;

    float poolv = 0.f;
    #pragma unroll
    for (int s = 0; s < 8; ++s) {
        const int qq = s*16 + co + g2;
        const int slot = (qq >> 1) + (qq & 1)*66;
        short8 afrag = *reinterpret_cast<const short8*>(&H[slot*8]);
        f32x4 d = __builtin_amdgcn_mfma_f32_16x16x32_bf16(afrag, bfrag, zacc, 0, 0, 0);
        poolv += fmaxf(d[0] + bias_c, 0.f);
        poolv += fmaxf(d[1] + bias_c, 0.f);
        poolv += fmaxf(d[2] + bias_c, 0.f);
        poolv += fmaxf(d[3] + bias_c, 0.f);
    }
    poolv += __shfl_xor(poolv, 16, 64);
    poolv += __shfl_xor(poolv, 32, 64);

    // linear 16 -> 8
    float rout = (lane < 8) ? l2b[lane] : 0.f;
    #pragma unroll
    for (int c = 0; c < 16; ++c) {
        float pc = __shfl(poolv, c, 64);
        if (lane < 8) rout = fmaf(pc * (1.f/128.f), l2w[c*8 + lane], rout);
    }
    // write readout (k 512..519 -> s=16, kc=0) + zero pad (kc 1..3)
    {
        const size_t qb = (qstep + 16u*4u)*512;
        if (lane < 4) {
            const int i0 = 2*lane, i1 = 2*lane + 1;
            float lo = __shfl(rout, i0, 64);
            float hi = __shfl(rout, i1, 64);
            uint w = (uint)f2bf(lo) | ((uint)f2bf(hi) << 16);
            *reinterpret_cast<uint*>(&xpadA[qb + r16*8 + lane*2]) = w;
        } else if (lane < 7) {
            const int kc = lane - 3;   // 1..3
            const uint4 z = make_uint4(0,0,0,0);
            *reinterpret_cast<uint4*>(&xpadA[qb + (kc*16 + r16)*8]) = z;
        }
    }
}

// ---------------- fused: lin_w -> BtT (frag-tiled) + degree count ----------------
__global__ __launch_bounds__(256) void k_prep(
    const float* __restrict__ lin_w, ushort* __restrict__ BtT,
    const int* __restrict__ dst, int* __restrict__ cursor, int E) {
    const int gid = blockIdx.x * 256 + threadIdx.x;
    if (gid < E) atomicAdd(&cursor[dst[gid]], 1);
    const int col = blockIdx.x;
    if (col < 256) {
        const int cs = col >> 4, fcol = col & 15;
        for (int k = threadIdx.x; k < 544; k += 256) {
            float v = (k < 520) ? lin_w[(size_t)k*256 + col] : 0.f;
            const int s = k >> 5, kc = (k >> 3) & 3, j = k & 7;
            BtT[(size_t)(s*16 + cs)*512 + (kc*16 + fcol)*8 + j] = f2bf(v);
        }
    }
}

// ---------------- single-pass block scan ----------------
__global__ __launch_bounds__(1024) void k_scan(int* __restrict__ deg, int* __restrict__ row_start, int N) {
    __shared__ int wsum[16];
    const int t = threadIdx.x;
    const int w = t >> 6, ln = t & 63;
    const int base = t * 20;
    int v[20];
    int run = 0;
    #pragma unroll
    for (int i = 0; i < 20; ++i) {
        const int idx = base + i;
        int d = 0;
        if (idx < N) { d = deg[idx]; deg[idx] = 0; }
        run += d;
        v[i] = run;
    }
    int s = run;
    #pragma unroll
    for (int d = 1; d < 64; d <<= 1) {
        int u = __shfl_up(s, d, 64);
        if (ln >= d) s += u;
    }
    if (ln == 63) wsum[w] = s;
    __syncthreads();
    if (w == 0) {
        int ws = (ln < 16) ? wsum[ln] : 0;
        int e2 = ws;
        #pragma unroll
        for (int d = 1; d < 16; d <<= 1) {
            int u = __shfl_up(e2, d, 64);
            if (ln >= d) e2 += u;
        }
        if (ln < 16) wsum[ln] = e2 - ws;
    }
    __syncthreads();
    const int off = (s - run) + wsum[w];
    if (t == 0) row_start[0] = 0;
    #pragma unroll
    for (int i = 0; i < 20; ++i) {
        const int idx = base + i;
        if (idx < N) row_start[idx + 1] = off + v[i];
    }
}

// ---------------- bf16-MFMA GEMM, 64x64 tile, coalesced frag-tiled loads, 2-deep pipeline ----------------
__global__ __launch_bounds__(128) void k_gemm_mfma(
    const ushort* __restrict__ xpadA, const ushort* __restrict__ BtT,
    const float* __restrict__ att_l, const float* __restrict__ att_r,
    ushort* __restrict__ xhb, float* __restrict__ al, float* __restrict__ ar,
    const int* __restrict__ src, const int* __restrict__ dst,
    const int* __restrict__ row_start, int* __restrict__ cursor, int* __restrict__ csr,
    int N, int E) {
    __shared__ __align__(16) float ep[64*68];

    const int t = threadIdx.x;
    const int wv = t >> 6, lane = t & 63;

    // bijective XCD swizzle (m204)
    const int nwg = gridDim.x;
    const int q = nwg >> 3, r = nwg & 7;
    const int xcd = blockIdx.x & 7, idx = blockIdx.x >> 3;
    const int logical = (xcd < r ? xcd*(q+1) : r*(q+1) + (xcd-r)*q) + idx;
    const int lt = logical >> 2;          // row tile (64 rows)
    const int c0s = (logical & 3) * 4;    // col-subtile base (of 16)
    const int m0 = lt * 64;

    // contiguous per-wave fragment loads: lane*8 ushorts within 512-ushort quarter
    const ushort* A0 = xpadA + ((size_t)(lt*17)*4 + wv*2    )*512 + lane*8;
    const ushort* A1 = A0 + 512;
    const ushort* B0 = BtT + (size_t)(c0s + 0)*512 + lane*8;
    const ushort* B1 = BtT + (size_t)(c0s + 1)*512 + lane*8;
    const ushort* B2 = BtT + (size_t)(c0s + 2)*512 + lane*8;
    const ushort* B3 = BtT + (size_t)(c0s + 3)*512 + lane*8;

    f32x4 acc0[4], acc1[4];
    #pragma unroll
    for (int j = 0; j < 4; ++j) { acc0[j] = (f32x4)0.f; acc1[j] = (f32x4)0.f; }

    short8 a0[2], a1[2], b0[2], b1[2], b2[2], b3[2];
#define LOADSET(B_, S_)                                                       \
    {                                                                         \
        a0[B_] = *reinterpret_cast<const short8*>(A0 + (size_t)(S_)*2048);    \
        a1[B_] = *reinterpret_cast<const short8*>(A1 + (size_t)(S_)*2048);    \
        b0[B_] = *reinterpret_cast<const short8*>(B0 + (size_t)(S_)*8192);    \
        b1[B_] = *reinterpret_cast<const short8*>(B1 + (size_t)(S_)*8192);    \
        b2[B_] = *reinterpret_cast<const short8*>(B2 + (size_t)(S_)*8192);    \
        b3[B_] = *reinterpret_cast<const short8*>(B3 + (size_t)(S_)*8192);    \
    }
    LOADSET(0, 0)
    #pragma unroll
    for (int s = 0; s < 17; ++s) {
        const int b = s & 1;
        if (s + 1 < 17) LOADSET((s + 1) & 1, s + 1)
        acc0[0] = __builtin_amdgcn_mfma_f32_16x16x32_bf16(a0[b], b0[b], acc0[0], 0, 0, 0);
        acc0[1] = __builtin_amdgcn_mfma_f32_16x16x32_bf16(a0[b], b1[b], acc0[1], 0, 0, 0);
        acc0[2] = __builtin_amdgcn_mfma_f32_16x16x32_bf16(a0[b], b2[b], acc0[2], 0, 0, 0);
        acc0[3] = __builtin_amdgcn_mfma_f32_16x16x32_bf16(a0[b], b3[b], acc0[3], 0, 0, 0);
        acc1[0] = __builtin_amdgcn_mfma_f32_16x16x32_bf16(a1[b], b0[b], acc1[0], 0, 0, 0);
        acc1[1] = __builtin_amdgcn_mfma_f32_16x16x32_bf16(a1[b], b1[b], acc1[1], 0, 0, 0);
        acc1[2] = __builtin_amdgcn_mfma_f32_16x16x32_bf16(a1[b], b2[b], acc1[2], 0, 0, 0);
        acc1[3] = __builtin_amdgcn_mfma_f32_16x16x32_bf16(a1[b], b3[b], acc1[3], 0, 0, 0);
    }
#undef LOADSET

    // fused CSR fill (2 edges/thread) — after the K-loop (R11 lesson)
    {
        const int e0 = blockIdx.x * 256 + t;
        if (e0 < E) {
            const int d = dst[e0];
            const int p = atomicAdd(&cursor[d], 1);
            csr[row_start[d] + p] = src[e0];
        }
        const int e1 = e0 + 128;
        if (e1 < E) {
            const int d = dst[e1];
            const int p = atomicAdd(&cursor[d], 1);
            csr[row_start[d] + p] = src[e1];
        }
    }

    // ---- epilogue: transpose through LDS; emit bf16 rows + al/ar (1 head per thread) ----
    {
        const int rb = wv*32 + ((lane >> 4) * 4);
        const int cb = lane & 15;
        #pragma unroll
        for (int j = 0; j < 4; ++j)
            #pragma unroll
            for (int r2 = 0; r2 < 4; ++r2) {
                ep[(rb      + r2)*68 + j*16 + cb] = acc0[j][r2];
                ep[(rb + 16 + r2)*68 + j*16 + cb] = acc1[j][r2];
            }
    }
    __syncthreads();
    {
        const int rl = t >> 1;
        const int cq = (t & 1) * 32;
        const int row = m0 + rl;
        if (row < N) {
            const int c0 = c0s * 16;
            const float* sp = &ep[rl*68 + cq];
            float vals[32];
            #pragma unroll
            for (int i = 0; i < 32; ++i) vals[i] = sp[i];
            uint u[16];
            #pragma unroll
            for (int i = 0; i < 16; ++i)
                u[i] = (uint)f2bf(vals[2*i]) | ((uint)f2bf(vals[2*i+1]) << 16);
            ushort* db = &xhb[(size_t)row*256 + c0 + cq];
            *reinterpret_cast<uint4*>(db)      = make_uint4(u[0], u[1], u[2], u[3]);
            *reinterpret_cast<uint4*>(db + 8)  = make_uint4(u[4], u[5], u[6], u[7]);
            *reinterpret_cast<uint4*>(db + 16) = make_uint4(u[8], u[9], u[10], u[11]);
            *reinterpret_cast<uint4*>(db + 24) = make_uint4(u[12], u[13], u[14], u[15]);
            float pl = 0.f, pr = 0.f;
            #pragma unroll
            for (int i = 0; i < 32; ++i) {
                pl = fmaf(vals[i], att_l[c0 + cq + i], pl);
                pr = fmaf(vals[i], att_r[c0 + cq + i], pr);
            }
            const int head = ((c0 + cq) >> 5);
            al[(size_t)row*8 + head] = pl;
            ar[(size_t)row*8 + head] = pr;
        }
    }
}

// ---------------- per-dst single-pass softmax aggregation (unroll x4) ----------------
__global__ __launch_bounds__(256) void k_agg(
    const ushort* __restrict__ xhb,
    const float* __restrict__ al, const float* __restrict__ ar,
    const float* __restrict__ onehot, const uint* __restrict__ ohb,
    const float* __restrict__ bias,
    const int* __restrict__ row_start, const int* __restrict__ csr,
    float* __restrict__ out_x, float* __restrict__ out_oh, int N) {
    const int wave = threadIdx.x >> 6;
    const int lane = threadIdx.x & 63;
    const int n = blockIdx.x * 4 + wave;
    if (n >= N) return;
    const int h = lane >> 3;
    const float ard = ar[(size_t)n*8 + h];

    float a_self = al[(size_t)n*8 + h] + ard;
    a_self = fmaxf(a_self, NEG_SLOPE * a_self);
    float e_self = __expf(a_self);
    uint2 xsb = *reinterpret_cast<const uint2*>(&xhb[(size_t)n*256 + lane*4]);
    float4 acc;
    acc.x = e_self * bflo(xsb.x); acc.y = e_self * bfhi(xsb.x);
    acc.z = e_self * bflo(xsb.y); acc.w = e_self * bfhi(xsb.y);
    float den = e_self;
    float oh0 = 0.f, oh1 = 0.f;

    const int beg = row_start[n], end = row_start[n+1];
    int i = beg;
    for (; i + 3 < end; i += 4) {
        const int s0 = csr[i], s1 = csr[i+1], s2 = csr[i+2], s3 = csr[i+3];
        const float al0 = al[(size_t)s0*8 + h], al1 = al[(size_t)s1*8 + h];
        const float al2 = al[(size_t)s2*8 + h], al3 = al[(size_t)s3*8 + h];
        const uint2 xb0 = *reinterpret_cast<const uint2*>(&xhb[(size_t)s0*256 + lane*4]);
        const uint2 xb1 = *reinterpret_cast<const uint2*>(&xhb[(size_t)s1*256 + lane*4]);
        const uint2 xb2 = *reinterpret_cast<const uint2*>(&xhb[(size_t)s2*256 + lane*4]);
        const uint2 xb3 = *reinterpret_cast<const uint2*>(&xhb[(size_t)s3*256 + lane*4]);
        const uint ob0 = ohb[(size_t)s0*64 + lane];
        const uint ob1 = ohb[(size_t)s1*64 + lane];
        const uint ob2 = ohb[(size_t)s2*64 + lane];
        const uint ob3 = ohb[(size_t)s3*64 + lane];
        float a0 = al0 + ard; a0 = fmaxf(a0, NEG_SLOPE * a0);
        float a1 = al1 + ard; a1 = fmaxf(a1, NEG_SLOPE * a1);
        float a2 = al2 + ard; a2 = fmaxf(a2, NEG_SLOPE * a2);
        float a3 = al3 + ard; a3 = fmaxf(a3, NEG_SLOPE * a3);
        const float e0 = __expf(a0), e1 = __expf(a1), e2 = __expf(a2), e3 = __expf(a3);
        acc.x = fmaf(e0, bflo(xb0.x), fmaf(e1, bflo(xb1.x), fmaf(e2, bflo(xb2.x), fmaf(e3, bflo(xb3.x), acc.x))));
        acc.y = fmaf(e0, bfhi(xb0.x), fmaf(e1, bfhi(xb1.x), fmaf(e2, bfhi(xb2.x), fmaf(e3, bfhi(xb3.x), acc.y))));
        acc.z = fmaf(e0, bflo(xb0.y), fmaf(e1, bflo(xb1.y), fmaf(e2, bflo(xb2.y), fmaf(e3, bflo(xb3.y), acc.z))));
        acc.w = fmaf(e0, bfhi(xb0.y), fmaf(e1, bfhi(xb1.y), fmaf(e2, bfhi(xb2.y), fmaf(e3, bfhi(xb3.y), acc.w))));
        den += (e0 + e1) + (e2 + e3);
        oh0 += (bflo(ob0) + bflo(ob1)) + (bflo(ob2) + bflo(ob3));
        oh1 += (bfhi(ob0) + bfhi(ob1)) + (bfhi(ob2) + bfhi(ob3));
    }
    for (; i < end; ++i) {
        const int s0 = csr[i];
        float a0 = al[(size_t)s0*8 + h] + ard;
        a0 = fmaxf(a0, NEG_SLOPE * a0);
        const float e0 = __expf(a0);
        const uint2 xb0 = *reinterpret_cast<const uint2*>(&xhb[(size_t)s0*256 + lane*4]);
        const uint ob0 = ohb[(size_t)s0*64 + lane];
        acc.x = fmaf(e0, bflo(xb0.x), acc.x);
        acc.y = fmaf(e0, bfhi(xb0.x), acc.y);
        acc.z = fmaf(e0, bflo(xb0.y), acc.z);
        acc.w = fmaf(e0, bfhi(xb0.y), acc.w);
        den += e0;
        oh0 += bflo(ob0);
        oh1 += bfhi(ob0);
    }
    const float inv = 1.f / den;
    const float4 bv = *reinterpret_cast<const float4*>(&bias[lane*4]);
    float4 o;
    o.x = fmaf(acc.x, inv, bv.x);
    o.y = fmaf(acc.y, inv, bv.y);
    o.z = fmaf(acc.z, inv, bv.z);
    o.w = fmaf(acc.w, inv, bv.w);
    *reinterpret_cast<float4*>(&out_x[(size_t)n*256 + lane*4]) = o;
    float2 so = *reinterpret_cast<const float2*>(&onehot[(size_t)n*128 + lane*2]);
    float2 oo;
    oo.x = oh0 + 2.f*so.x;
    oo.y = oh1 + 2.f*so.y;
    *reinterpret_cast<float2*>(&out_oh[(size_t)n*128 + lane*2]) = oo;
}

// ---------------- launcher ----------------
extern "C" void kernel_launch(void* const* d_in, const int* in_sizes, int n_in,
                              void* d_out, int out_size, void* d_ws, size_t ws_size,
                              hipStream_t stream) {
    const float* x      = (const float*)d_in[0];
    const float* onehot = (const float*)d_in[1];
    const int*   adj    = (const int*)d_in[2];
    const float* lin_w  = (const float*)d_in[4];
    const float* att_l  = (const float*)d_in[5];
    const float* att_r  = (const float*)d_in[6];
    const float* bias   = (const float*)d_in[7];
    const float* c1w    = (const float*)d_in[8];
    const float* c1b    = (const float*)d_in[9];
    const float* c2w    = (const float*)d_in[10];
    const float* c2b    = (const float*)d_in[11];
    const float* l2w    = (const float*)d_in[12];
    const float* l2b    = (const float*)d_in[13];

    const int N = in_sizes[0] / 512;
    const int E = in_sizes[2] / 2;
    const int* src = adj;
    const int* dst = adj + E;

    float* out_x  = (float*)d_out;
    float* out_oh = out_x + (size_t)N * 256;

    const int NT = (N + 63) / 64;

    // workspace layout
    ushort* xpadA    = (ushort*)d_ws;                       // NT*17*2048 ushorts (frag-tiled)
    ushort* BtT      = xpadA + (size_t)NT * 17 * 2048;      // 17*8192 ushorts
    ushort* xhb      = BtT + (size_t)17 * 8192;             // N*256 bf16
    uint*   ohb      = (uint*)(xhb + (size_t)N * 256);      // N*64 packed bf16x2
    float*  al       = (float*)(ohb + (size_t)N * 64);      // N*8
    float*  ar       = al + (size_t)N * 8;                  // N*8
    int*   row_start = (int*)(ar + (size_t)N * 8);          // N+1
    int*   cursor    = row_start + (N + 1);                 // N
    int*   csr       = cursor + N;                          // E

    const int EB = (E + 255) / 256;
    const int GB = NT * 4;

    k_conv_wave<<<(N + 3) / 4, 256, 0, stream>>>(x, onehot, c1w, c1b, c2w, c2b, l2w, l2b, xpadA, ohb, cursor, N);
    k_prep<<<EB, 256, 0, stream>>>(lin_w, BtT, dst, cursor, E);
    k_scan<<<1, 1024, 0, stream>>>(cursor, row_start, N);
    k_gemm_mfma<<<GB, 128, 0, stream>>>(xpadA, BtT, att_l, att_r, xhb, al, ar,
                                        src, dst, row_start, cursor, csr, N, E);
    k_agg<<<(N + 3) / 4, 256, 0, stream>>>(xhb, al, ar, onehot, ohb, bias, row_start, csr, out_x, out_oh, N);
}

// Round 14
// 163.470 us; speedup vs baseline: 1.1983x; 1.0040x over previous
//
#include <hip/hip_runtime.h>

#define NEG_SLOPE 0.2f

typedef __attribute__((ext_vector_type(4))) float f32x4;
typedef __attribute__((ext_vector_type(2))) float f32x2;
typedef __attribute__((ext_vector_type(8))) short short8;

__device__ __forceinline__ f32x2 mk2(float a, float b) { f32x2 r; r[0] = a; r[1] = b; return r; }

__device__ __forceinline__ f32x2 FMA2(f32x2 a, f32x2 b, f32x2 c) {
#if __has_builtin(__builtin_elementwise_fma)
    return __builtin_elementwise_fma(a, b, c);
#else
    f32x2 r; r[0] = fmaf(a[0], b[0], c[0]); r[1] = fmaf(a[1], b[1], c[1]); return r;
#endif
}

__device__ __forceinline__ ushort f2bf(float f) {
    uint u = __float_as_uint(f);
    u += 0x7FFFu + ((u >> 16) & 1u);
    return (ushort)(u >> 16);
}
__device__ __forceinline__ float bflo(uint u) { return __uint_as_float(u << 16); }
__device__ __forceinline__ float bfhi(uint u) { return __uint_as_float(u & 0xffff0000u); }

// xpadA fragment-tiled layout: element (n,k) ->
//   nt=n>>6, g16=(n>>4)&3, r16=n&15, s=k>>5, kc=(k>>3)&3, j=k&7
//   ushort addr = ((nt*17+s)*4 + g16)*512 + (kc*16+r16)*8 + j
// BtT: (col,k) -> s=k>>5, cs=col>>4, fcol=col&15
//   ushort addr = (s*16+cs)*512 + (kc*16+fcol)*8 + j

// ---------------- conv pipe (conv2 via MFMA) + x->bf16 frag-tiled prep + cursor zero ----------------
__global__ __launch_bounds__(256) void k_conv_wave(
    const float* __restrict__ x, const float* __restrict__ onehot,
    const float* __restrict__ c1w, const float* __restrict__ c1b,
    const float* __restrict__ c2w, const float* __restrict__ c2b,
    const float* __restrict__ l2w, const float* __restrict__ l2b,
    ushort* __restrict__ xpadA, uint* __restrict__ ohb, int* __restrict__ cursor, int N) {
    __shared__ ushort Hall[4][1056];

    const int gid = blockIdx.x * 256 + threadIdx.x;
    if (gid < N) cursor[gid] = 0;

    const int wave = threadIdx.x >> 6;
    const int lane = threadIdx.x & 63;
    const int n = blockIdx.x * 4 + wave;
    if (n >= N) return;
    ushort* H = Hall[wave];

    const int nt = n >> 6, g16 = (n >> 4) & 3, r16 = n & 15;
    const size_t qstep = ((size_t)nt*17)*4 + g16;

    // fused prepX: lane l holds k = l*8..l*8+7  ->  s=l>>2, kc=l&3
    {
        const float* xp = &x[(size_t)n*512 + lane*8];
        float4 lo = *reinterpret_cast<const float4*>(xp);
        float4 hi = *reinterpret_cast<const float4*>(xp + 4);
        uint4 w;
        w.x = (uint)f2bf(lo.x) | ((uint)f2bf(lo.y) << 16);
        w.y = (uint)f2bf(lo.z) | ((uint)f2bf(lo.w) << 16);
        w.z = (uint)f2bf(hi.x) | ((uint)f2bf(hi.y) << 16);
        w.w = (uint)f2bf(hi.z) | ((uint)f2bf(hi.w) << 16);
        const size_t a = (qstep + (size_t)(lane >> 2)*4)*512 + ((lane & 3)*16 + r16)*8;
        *reinterpret_cast<uint4*>(&xpadA[a]) = w;
    }

    float2 in2 = *reinterpret_cast<const float2*>(&onehot[(size_t)n * 128 + lane * 2]);
    ohb[(size_t)n*64 + lane] = (uint)f2bf(in2.x) | ((uint)f2bf(in2.y) << 16);
    float v0 = log1pf(in2.x);
    float v1 = log1pf(in2.y);

    // bitonic sort of 128 elements, fully in registers
    #pragma unroll
    for (int k = 2; k <= 128; k <<= 1) {
        const bool asc = ((lane & (k >> 1)) == 0);
        #pragma unroll
        for (int j = k >> 1; j >= 2; j >>= 1) {
            const int m = j >> 1;
            float p0 = __shfl_xor(v0, m, 64);
            float p1 = __shfl_xor(v1, m, 64);
            const bool keepmin = (((lane & m) == 0) == asc);
            v0 = keepmin ? fminf(v0, p0) : fmaxf(v0, p0);
            v1 = keepmin ? fminf(v1, p1) : fmaxf(v1, p1);
        }
        float lo = fminf(v0, v1), hi = fmaxf(v0, v1);
        v0 = asc ? lo : hi;
        v1 = asc ? hi : lo;
    }

    float pm = __shfl_up(v1, 1, 64); if (lane == 0)  pm = 0.f;
    float pp = __shfl_down(v0, 1, 64); if (lane == 63) pp = 0.f;

    float h0[8], h1[8];
    {
        const f32x2 xm = mk2(pm, v0), x0 = mk2(v0, v1), xp2 = mk2(v1, pp);
        #pragma unroll
        for (int c = 0; c < 8; ++c) {
            const float w0 = c1w[c*3+0], w1 = c1w[c*3+1], w2 = c1w[c*3+2], b = c1b[c];
            f32x2 h = FMA2(xm, mk2(w0, w0), FMA2(x0, mk2(w1, w1), FMA2(xp2, mk2(w2, w2), mk2(b, b))));
            h0[c] = fmaxf(h[0], 0.f);
            h1[c] = fmaxf(h[1], 0.f);
        }
    }

    // stage h (bf16) into LDS rows; zero boundary rows
    {
        if (lane == 0) {
            const uint4 z = make_uint4(0,0,0,0);
            *reinterpret_cast<uint4*>(&H[0*8])   = z;
            *reinterpret_cast<uint4*>(&H[130*8]) = z;
            *reinterpret_cast<uint4*>(&H[65*8])  = z;
        }
        uint4 w0, w1;
        w0.x = (uint)f2bf(h0[0]) | ((uint)f2bf(h0[1]) << 16);
        w0.y = (uint)f2bf(h0[2]) | ((uint)f2bf(h0[3]) << 16);
        w0.z = (uint)f2bf(h0[4]) | ((uint)f2bf(h0[5]) << 16);
        w0.w = (uint)f2bf(h0[6]) | ((uint)f2bf(h0[7]) << 16);
        w1.x = (uint)f2bf(h1[0]) | ((uint)f2bf(h1[1]) << 16);
        w1.y = (uint)f2bf(h1[2]) | ((uint)f2bf(h1[3]) << 16);
        w1.z = (uint)f2bf(h1[4]) | ((uint)f2bf(h1[5]) << 16);
        w1.w = (uint)f2bf(h1[6]) | ((uint)f2bf(h1[7]) << 16);
        *reinterpret_cast<uint4*>(&H[(66 + lane)*8]) = w0;
        *reinterpret_cast<uint4*>(&H[(lane + 1)*8])  = w1;
    }

    // conv2 as MFMA
    const int co = lane & 15;
    const int g2 = lane >> 4;
    short8 bfrag;
    #pragma unroll
    for (int j = 0; j < 8; ++j) bfrag[j] = 0;
    if (g2 < 3) {
        #pragma unroll
        for (int j = 0; j < 8; ++j) bfrag[j] = (short)f2bf(c2w[(co*8 + j)*3 + g2]);
    }
    const float bias_c = c2b[co];
    const f32x4 zacc = (f32x4)0.f;

    float poolv = 0.f;
    #pragma unroll
    for (int s = 0; s < 8; ++s) {
        const int qq = s*16 + co + g2;
        const int slot = (qq >> 1) + (qq & 1)*66;
        short8 afrag = *reinterpret_cast<const short8*>(&H[slot*8]);
        f32x4 d = __builtin_amdgcn_mfma_f32_16x16x32_bf16(afrag, bfrag, zacc, 0, 0, 0);
        poolv += fmaxf(d[0] + bias_c, 0.f);
        poolv += fmaxf(d[1] + bias_c, 0.f);
        poolv += fmaxf(d[2] + bias_c, 0.f);
        poolv += fmaxf(d[3] + bias_c, 0.f);
    }
    poolv += __shfl_xor(poolv, 16, 64);
    poolv += __shfl_xor(poolv, 32, 64);

    // linear 16 -> 8
    float rout = (lane < 8) ? l2b[lane] : 0.f;
    #pragma unroll
    for (int c = 0; c < 16; ++c) {
        float pc = __shfl(poolv, c, 64);
        if (lane < 8) rout = fmaf(pc * (1.f/128.f), l2w[c*8 + lane], rout);
    }
    // write readout (k 512..519 -> s=16, kc=0) + zero pad (kc 1..3)
    {
        const size_t qb = (qstep + 16u*4u)*512;
        if (lane < 4) {
            const int i0 = 2*lane, i1 = 2*lane + 1;
            float lo = __shfl(rout, i0, 64);
            float hi = __shfl(rout, i1, 64);
            uint w = (uint)f2bf(lo) | ((uint)f2bf(hi) << 16);
            *reinterpret_cast<uint*>(&xpadA[qb + r16*8 + lane*2]) = w;
        } else if (lane < 7) {
            const int kc = lane - 3;
            const uint4 z = make_uint4(0,0,0,0);
            *reinterpret_cast<uint4*>(&xpadA[qb + (kc*16 + r16)*8]) = z;
        }
    }
}

// ---------------- fused: lin_w -> BtT (frag-tiled) + degree count ----------------
__global__ __launch_bounds__(256) void k_prep(
    const float* __restrict__ lin_w, ushort* __restrict__ BtT,
    const int* __restrict__ dst, int* __restrict__ cursor, int E) {
    const int gid = blockIdx.x * 256 + threadIdx.x;
    if (gid < E) atomicAdd(&cursor[dst[gid]], 1);
    const int col = blockIdx.x;
    if (col < 256) {
        const int cs = col >> 4, fcol = col & 15;
        for (int k = threadIdx.x; k < 544; k += 256) {
            float v = (k < 520) ? lin_w[(size_t)k*256 + col] : 0.f;
            const int s = k >> 5, kc = (k >> 3) & 3, j = k & 7;
            BtT[(size_t)(s*16 + cs)*512 + (kc*16 + fcol)*8 + j] = f2bf(v);
        }
    }
}

// ---------------- single-pass block scan ----------------
__global__ __launch_bounds__(1024) void k_scan(int* __restrict__ deg, int* __restrict__ row_start, int N) {
    __shared__ int wsum[16];
    const int t = threadIdx.x;
    const int w = t >> 6, ln = t & 63;
    const int base = t * 20;
    int v[20];
    int run = 0;
    #pragma unroll
    for (int i = 0; i < 20; ++i) {
        const int idx = base + i;
        int d = 0;
        if (idx < N) { d = deg[idx]; deg[idx] = 0; }
        run += d;
        v[i] = run;
    }
    int s = run;
    #pragma unroll
    for (int d = 1; d < 64; d <<= 1) {
        int u = __shfl_up(s, d, 64);
        if (ln >= d) s += u;
    }
    if (ln == 63) wsum[w] = s;
    __syncthreads();
    if (w == 0) {
        int ws = (ln < 16) ? wsum[ln] : 0;
        int e2 = ws;
        #pragma unroll
        for (int d = 1; d < 16; d <<= 1) {
            int u = __shfl_up(e2, d, 64);
            if (ln >= d) e2 += u;
        }
        if (ln < 16) wsum[ln] = e2 - ws;
    }
    __syncthreads();
    const int off = (s - run) + wsum[w];
    if (t == 0) row_start[0] = 0;
    #pragma unroll
    for (int i = 0; i < 20; ++i) {
        const int idx = base + i;
        if (idx < N) row_start[idx + 1] = off + v[i];
    }
}

// ---------------- bf16-MFMA GEMM, 64x32 tile, 4-deep pipeline, coalesced frag-tiled loads ----------------
__global__ __launch_bounds__(128) void k_gemm_mfma(
    const ushort* __restrict__ xpadA, const ushort* __restrict__ BtT,
    const float* __restrict__ att_l, const float* __restrict__ att_r,
    ushort* __restrict__ xhb, float* __restrict__ al, float* __restrict__ ar,
    const int* __restrict__ src, const int* __restrict__ dst,
    const int* __restrict__ row_start, int* __restrict__ cursor, int* __restrict__ csr,
    int N, int E) {
    __shared__ __align__(16) float ep[64*36];

    const int t = threadIdx.x;
    const int wv = t >> 6, lane = t & 63;

    // bijective XCD swizzle (m204)
    const int nwg = gridDim.x;
    const int q = nwg >> 3, r = nwg & 7;
    const int xcd = blockIdx.x & 7, idx = blockIdx.x >> 3;
    const int logical = (xcd < r ? xcd*(q+1) : r*(q+1) + (xcd-r)*q) + idx;
    const int lt = logical >> 3;          // row tile (64 rows)
    const int ch = logical & 7;           // col half (32 cols = 1 head)
    const int m0 = lt * 64;
    const int c0 = ch * 32;
    const int cs = ch * 2;                // col-subtile base

    const ushort* A0 = xpadA + ((size_t)(lt*17)*4 + wv*2)*512 + lane*8;
    const ushort* A1 = A0 + 512;
    const ushort* B0 = BtT + (size_t)(cs + 0)*512 + lane*8;
    const ushort* B1 = BtT + (size_t)(cs + 1)*512 + lane*8;

    f32x4 acc00 = (f32x4)0.f, acc01 = (f32x4)0.f, acc10 = (f32x4)0.f, acc11 = (f32x4)0.f;

    short8 a0[4], a1[4], b0[4], b1[4];
#define LOADSET(B_, S_)                                                       \
    {                                                                         \
        a0[B_] = *reinterpret_cast<const short8*>(A0 + (size_t)(S_)*2048);    \
        a1[B_] = *reinterpret_cast<const short8*>(A1 + (size_t)(S_)*2048);    \
        b0[B_] = *reinterpret_cast<const short8*>(B0 + (size_t)(S_)*8192);    \
        b1[B_] = *reinterpret_cast<const short8*>(B1 + (size_t)(S_)*8192);    \
    }
    LOADSET(0, 0)
    LOADSET(1, 1)
    LOADSET(2, 2)
    #pragma unroll
    for (int s = 0; s < 17; ++s) {
        const int b = s & 3;
        if (s + 3 < 17) LOADSET((s + 3) & 3, s + 3)
        acc00 = __builtin_amdgcn_mfma_f32_16x16x32_bf16(a0[b], b0[b], acc00, 0, 0, 0);
        acc01 = __builtin_amdgcn_mfma_f32_16x16x32_bf16(a0[b], b1[b], acc01, 0, 0, 0);
        acc10 = __builtin_amdgcn_mfma_f32_16x16x32_bf16(a1[b], b0[b], acc10, 0, 0, 0);
        acc11 = __builtin_amdgcn_mfma_f32_16x16x32_bf16(a1[b], b1[b], acc11, 0, 0, 0);
    }
#undef LOADSET

    // fused CSR fill (1 edge/thread) — after the K-loop (R11 lesson: vmcnt is oldest-first)
    {
        const int e = blockIdx.x * 128 + t;
        if (e < E) {
            const int d = dst[e];
            const int p = atomicAdd(&cursor[d], 1);
            csr[row_start[d] + p] = src[e];
        }
    }

    // ---- epilogue: transpose through LDS; emit bf16 rows + al/ar (1 head per row-pair) ----
    {
        const int rq = (lane >> 4) * 4;
        const int cb = lane & 15;
        #pragma unroll
        for (int r2 = 0; r2 < 4; ++r2) {
            ep[(wv*32 +      rq + r2)*36 +      cb] = acc00[r2];
            ep[(wv*32 +      rq + r2)*36 + 16 + cb] = acc01[r2];
            ep[(wv*32 + 16 + rq + r2)*36 +      cb] = acc10[r2];
            ep[(wv*32 + 16 + rq + r2)*36 + 16 + cb] = acc11[r2];
        }
    }
    __syncthreads();
    {
        const int rl = t >> 1;
        const int half = t & 1;
        const int row = m0 + rl;
        if (row < N) {
            const float* sp = &ep[rl*36 + half*16];
            float vals[16];
            #pragma unroll
            for (int i = 0; i < 16; ++i) vals[i] = sp[i];
            uint u[8];
            #pragma unroll
            for (int i = 0; i < 8; ++i)
                u[i] = (uint)f2bf(vals[2*i]) | ((uint)f2bf(vals[2*i+1]) << 16);
            ushort* db = &xhb[(size_t)row*256 + c0 + half*16];
            *reinterpret_cast<uint4*>(db)     = make_uint4(u[0], u[1], u[2], u[3]);
            *reinterpret_cast<uint4*>(db + 8) = make_uint4(u[4], u[5], u[6], u[7]);
            float pl = 0.f, pr = 0.f;
            #pragma unroll
            for (int i = 0; i < 16; ++i) {
                pl = fmaf(vals[i], att_l[c0 + half*16 + i], pl);
                pr = fmaf(vals[i], att_r[c0 + half*16 + i], pr);
            }
            pl += __shfl_xor(pl, 1, 64);
            pr += __shfl_xor(pr, 1, 64);
            if (half == 0) {
                al[(size_t)row*8 + ch] = pl;
                ar[(size_t)row*8 + ch] = pr;
            }
        }
    }
}

// ---------------- per-dst single-pass softmax aggregation: 2 nodes/wave, 32 lanes/node ----------------
__global__ __launch_bounds__(256) void k_agg(
    const ushort* __restrict__ xhb,
    const float* __restrict__ al, const float* __restrict__ ar,
    const float* __restrict__ onehot, const uint* __restrict__ ohb,
    const float* __restrict__ bias,
    const int* __restrict__ row_start, const int* __restrict__ csr,
    float* __restrict__ out_x, float* __restrict__ out_oh, int N) {
    const int wave = threadIdx.x >> 6;
    const int lane = threadIdx.x & 63;
    const int half = lane >> 5;
    const int ln = lane & 31;
    const int n = blockIdx.x * 8 + wave * 2 + half;
    if (n >= N) return;
    const int h = ln >> 2;
    const float ard = ar[(size_t)n*8 + h];

    float a_self = al[(size_t)n*8 + h] + ard;
    a_self = fmaxf(a_self, NEG_SLOPE * a_self);
    float e_self = __expf(a_self);
    uint4 xsb = *reinterpret_cast<const uint4*>(&xhb[(size_t)n*256 + ln*8]);
    float acc0 = e_self * bflo(xsb.x), acc1 = e_self * bfhi(xsb.x);
    float acc2 = e_self * bflo(xsb.y), acc3 = e_self * bfhi(xsb.y);
    float acc4 = e_self * bflo(xsb.z), acc5 = e_self * bfhi(xsb.z);
    float acc6 = e_self * bflo(xsb.w), acc7 = e_self * bfhi(xsb.w);
    float den = e_self;
    float oh0 = 0.f, oh1 = 0.f, oh2 = 0.f, oh3 = 0.f;

    const int beg = row_start[n], end = row_start[n+1];
    int i = beg;
    for (; i + 1 < end; i += 2) {
        const int s0 = csr[i], s1 = csr[i+1];
        const float al0 = al[(size_t)s0*8 + h], al1 = al[(size_t)s1*8 + h];
        const uint4 x0 = *reinterpret_cast<const uint4*>(&xhb[(size_t)s0*256 + ln*8]);
        const uint4 x1 = *reinterpret_cast<const uint4*>(&xhb[(size_t)s1*256 + ln*8]);
        const uint2 o0 = *reinterpret_cast<const uint2*>(&ohb[(size_t)s0*64 + ln*2]);
        const uint2 o1 = *reinterpret_cast<const uint2*>(&ohb[(size_t)s1*64 + ln*2]);
        float a0 = al0 + ard; a0 = fmaxf(a0, NEG_SLOPE * a0);
        float a1 = al1 + ard; a1 = fmaxf(a1, NEG_SLOPE * a1);
        const float e0 = __expf(a0), e1 = __expf(a1);
        acc0 = fmaf(e0, bflo(x0.x), fmaf(e1, bflo(x1.x), acc0));
        acc1 = fmaf(e0, bfhi(x0.x), fmaf(e1, bfhi(x1.x), acc1));
        acc2 = fmaf(e0, bflo(x0.y), fmaf(e1, bflo(x1.y), acc2));
        acc3 = fmaf(e0, bfhi(x0.y), fmaf(e1, bfhi(x1.y), acc3));
        acc4 = fmaf(e0, bflo(x0.z), fmaf(e1, bflo(x1.z), acc4));
        acc5 = fmaf(e0, bfhi(x0.z), fmaf(e1, bfhi(x1.z), acc5));
        acc6 = fmaf(e0, bflo(x0.w), fmaf(e1, bflo(x1.w), acc6));
        acc7 = fmaf(e0, bfhi(x0.w), fmaf(e1, bfhi(x1.w), acc7));
        den += e0 + e1;
        oh0 += bflo(o0.x) + bflo(o1.x);
        oh1 += bfhi(o0.x) + bfhi(o1.x);
        oh2 += bflo(o0.y) + bflo(o1.y);
        oh3 += bfhi(o0.y) + bfhi(o1.y);
    }
    if (i < end) {
        const int s0 = csr[i];
        float a0 = al[(size_t)s0*8 + h] + ard;
        a0 = fmaxf(a0, NEG_SLOPE * a0);
        const float e0 = __expf(a0);
        const uint4 x0 = *reinterpret_cast<const uint4*>(&xhb[(size_t)s0*256 + ln*8]);
        const uint2 o0 = *reinterpret_cast<const uint2*>(&ohb[(size_t)s0*64 + ln*2]);
        acc0 = fmaf(e0, bflo(x0.x), acc0);
        acc1 = fmaf(e0, bfhi(x0.x), acc1);
        acc2 = fmaf(e0, bflo(x0.y), acc2);
        acc3 = fmaf(e0, bfhi(x0.y), acc3);
        acc4 = fmaf(e0, bflo(x0.z), acc4);
        acc5 = fmaf(e0, bfhi(x0.z), acc5);
        acc6 = fmaf(e0, bflo(x0.w), acc6);
        acc7 = fmaf(e0, bfhi(x0.w), acc7);
        den += e0;
        oh0 += bflo(o0.x);
        oh1 += bfhi(o0.x);
        oh2 += bflo(o0.y);
        oh3 += bfhi(o0.y);
    }
    const float inv = 1.f / den;
    const float4 bv0 = *reinterpret_cast<const float4*>(&bias[ln*8]);
    const float4 bv1 = *reinterpret_cast<const float4*>(&bias[ln*8 + 4]);
    float4 q0, q1;
    q0.x = fmaf(acc0, inv, bv0.x); q0.y = fmaf(acc1, inv, bv0.y);
    q0.z = fmaf(acc2, inv, bv0.z); q0.w = fmaf(acc3, inv, bv0.w);
    q1.x = fmaf(acc4, inv, bv1.x); q1.y = fmaf(acc5, inv, bv1.y);
    q1.z = fmaf(acc6, inv, bv1.z); q1.w = fmaf(acc7, inv, bv1.w);
    *reinterpret_cast<float4*>(&out_x[(size_t)n*256 + ln*8])     = q0;
    *reinterpret_cast<float4*>(&out_x[(size_t)n*256 + ln*8 + 4]) = q1;
    const float4 so = *reinterpret_cast<const float4*>(&onehot[(size_t)n*128 + ln*4]);
    float4 oo;
    oo.x = oh0 + 2.f*so.x;
    oo.y = oh1 + 2.f*so.y;
    oo.z = oh2 + 2.f*so.z;
    oo.w = oh3 + 2.f*so.w;
    *reinterpret_cast<float4*>(&out_oh[(size_t)n*128 + ln*4]) = oo;
}

// ---------------- launcher ----------------
extern "C" void kernel_launch(void* const* d_in, const int* in_sizes, int n_in,
                              void* d_out, int out_size, void* d_ws, size_t ws_size,
                              hipStream_t stream) {
    const float* x      = (const float*)d_in[0];
    const float* onehot = (const float*)d_in[1];
    const int*   adj    = (const int*)d_in[2];
    const float* lin_w  = (const float*)d_in[4];
    const float* att_l  = (const float*)d_in[5];
    const float* att_r  = (const float*)d_in[6];
    const float* bias   = (const float*)d_in[7];
    const float* c1w    = (const float*)d_in[8];
    const float* c1b    = (const float*)d_in[9];
    const float* c2w    = (const float*)d_in[10];
    const float* c2b    = (const float*)d_in[11];
    const float* l2w    = (const float*)d_in[12];
    const float* l2b    = (const float*)d_in[13];

    const int N = in_sizes[0] / 512;
    const int E = in_sizes[2] / 2;
    const int* src = adj;
    const int* dst = adj + E;

    float* out_x  = (float*)d_out;
    float* out_oh = out_x + (size_t)N * 256;

    const int NT = (N + 63) / 64;

    // workspace layout
    ushort* xpadA    = (ushort*)d_ws;                       // NT*17*2048 ushorts (frag-tiled)
    ushort* BtT      = xpadA + (size_t)NT * 17 * 2048;      // 17*8192 ushorts
    ushort* xhb      = BtT + (size_t)17 * 8192;             // N*256 bf16
    uint*   ohb      = (uint*)(xhb + (size_t)N * 256);      // N*64 packed bf16x2
    float*  al       = (float*)(ohb + (size_t)N * 64);      // N*8
    float*  ar       = al + (size_t)N * 8;                  // N*8
    int*   row_start = (int*)(ar + (size_t)N * 8);          // N+1
    int*   cursor    = row_start + (N + 1);                 // N
    int*   csr       = cursor + N;                          // E

    const int EB = (E + 255) / 256;
    const int GB = NT * 8;

    k_conv_wave<<<(N + 3) / 4, 256, 0, stream>>>(x, onehot, c1w, c1b, c2w, c2b, l2w, l2b, xpadA, ohb, cursor, N);
    k_prep<<<EB, 256, 0, stream>>>(lin_w, BtT, dst, cursor, E);
    k_scan<<<1, 1024, 0, stream>>>(cursor, row_start, N);
    k_gemm_mfma<<<GB, 128, 0, stream>>>(xpadA, BtT, att_l, att_r, xhb, al, ar,
                                        src, dst, row_start, cursor, csr, N, E);
    k_agg<<<(N + 7) / 8, 256, 0, stream>>>(xhb, al, ar, onehot, ohb, bias, row_start, csr, out_x, out_oh, N);
}